// Round 1
// baseline (971.243 us; speedup 1.0000x reference)
//
#include <hip/hip_runtime.h>

#define C 128
#define KORD 6
#define TM 64

// ---------- monotone float<->uint encoding for atomicMax over floats ----------
__device__ __forceinline__ unsigned enc_f32(float f) {
  unsigned u = __float_as_uint(f);
  return (u & 0x80000000u) ? ~u : (u | 0x80000000u);
}
__device__ __forceinline__ float dec_f32(unsigned u) {
  return (u & 0x80000000u) ? __uint_as_float(u ^ 0x80000000u) : __uint_as_float(~u);
}

// ---------- bias sum: bsum[c] = sum_k b_dense[k][c] + bias[c] ----------
__global__ void bsum_kernel(const float* __restrict__ bd, const float* __restrict__ bias,
                            float* __restrict__ bsum) {
  int c = threadIdx.x;
  float s = bias[c];
#pragma unroll
  for (int k = 0; k < KORD; ++k) s += bd[k * C + c];
  bsum[c] = s;
}

// ---------- CSR build: histogram ----------
__global__ void hist_kernel(const int* __restrict__ senders, int ne, int* __restrict__ counts) {
  int e = blockIdx.x * blockDim.x + threadIdx.x;
  if (e < ne) atomicAdd(&counts[senders[e]], 1);
}

// ---------- single-block exclusive scan over counts -> offsets[0..n] ----------
__global__ void scan_kernel(const int* __restrict__ counts, int* __restrict__ offsets, int n) {
  __shared__ int sm[1024];
  __shared__ int carry;
  int t = threadIdx.x;
  if (t == 0) carry = 0;
  __syncthreads();
  for (int base = 0; base < n; base += 1024) {
    int i = base + t;
    int v = (i < n) ? counts[i] : 0;
    sm[t] = v;
    __syncthreads();
    for (int d = 1; d < 1024; d <<= 1) {
      int a = (t >= d) ? sm[t - d] : 0;
      __syncthreads();
      sm[t] += a;
      __syncthreads();
    }
    if (i < n) offsets[i] = carry + sm[t] - v;  // exclusive
    int total = sm[1023];
    __syncthreads();
    if (t == 0) carry += total;
    __syncthreads();
  }
  if (t == 0) offsets[n] = carry;
}

// ---------- scatter edges into CSR order ----------
__global__ void scatter_kernel(const int* __restrict__ senders, const int* __restrict__ receivers,
                               const float* __restrict__ edges, int ne,
                               const int* __restrict__ offsets, int* __restrict__ cursor,
                               float* __restrict__ csr_w, int* __restrict__ csr_r) {
  int e = blockIdx.x * blockDim.x + threadIdx.x;
  if (e >= ne) return;
  int s = senders[e];
  int p = offsets[s] + atomicAdd(&cursor[s], 1);
  csr_w[p] = edges[e];
  csr_r[p] = receivers[e];
}

// ---------- deg[i] = row sum of csr_w; fused max-reduce into umax ----------
__global__ void deg_kernel(const int* __restrict__ offsets, const float* __restrict__ csr_w,
                           int n, float* __restrict__ deg, unsigned* __restrict__ umax) {
  int i = blockIdx.x * blockDim.x + threadIdx.x;
  float d = 0.f;
  if (i < n) {
    int e0 = offsets[i], e1 = offsets[i + 1];
    for (int e = e0; e < e1; ++e) d += csr_w[e];
    deg[i] = d;
  }
  float m = (i < n) ? d : 0.f;  // deg >= 0, so 0 filler is safe
#pragma unroll
  for (int off = 32; off > 0; off >>= 1) m = fmaxf(m, __shfl_down(m, off, 64));
  if ((threadIdx.x & 63) == 0) atomicMax(umax, enc_f32(m));
}

// ---------- max over (-edges) ----------
__global__ void negedge_max_kernel(const float* __restrict__ edges, int ne,
                                   unsigned* __restrict__ umax) {
  int i = blockIdx.x * blockDim.x + threadIdx.x;
  float m = -INFINITY;
  for (int e = i; e < ne; e += gridDim.x * blockDim.x) m = fmaxf(m, -edges[e]);
#pragma unroll
  for (int off = 32; off > 0; off >>= 1) m = fmaxf(m, __shfl_down(m, off, 64));
  if ((threadIdx.x & 63) == 0) atomicMax(umax, enc_f32(m));
}

// ---------- scale = 2/lambda_max = 1/max ----------
__global__ void scale_kernel(const unsigned* __restrict__ umax, float* __restrict__ scalep) {
  *scalep = 1.0f / dec_f32(*umax);
}

// ---------- y = coef*scale*(deg*x - A_gather(x)) - z   (one wave per node) ----------
__global__ __launch_bounds__(256) void matvec_kernel(
    float* __restrict__ y, const float* __restrict__ x, const float* __restrict__ z,
    const float* __restrict__ deg, const int* __restrict__ offsets,
    const float* __restrict__ csr_w, const int* __restrict__ csr_r,
    const float* __restrict__ scalep, float coef, int n) {
  int wid = (blockIdx.x * blockDim.x + threadIdx.x) >> 6;
  int lane = threadIdx.x & 63;
  if (wid >= n) return;
  float sc = scalep[0] * coef;
  int e0 = offsets[wid], e1 = offsets[wid + 1];
  const float2* x2 = (const float2*)x;
  float ax = 0.f, ay = 0.f;
  int e = e0;
  for (; e + 1 < e1; e += 2) {
    float w0 = csr_w[e], w1 = csr_w[e + 1];
    int r0 = csr_r[e], r1 = csr_r[e + 1];
    float2 v0 = x2[(size_t)r0 * 64 + lane];
    float2 v1 = x2[(size_t)r1 * 64 + lane];
    ax = fmaf(w0, v0.x, ax); ay = fmaf(w0, v0.y, ay);
    ax = fmaf(w1, v1.x, ax); ay = fmaf(w1, v1.y, ay);
  }
  if (e < e1) {
    float w0 = csr_w[e];
    int r0 = csr_r[e];
    float2 v0 = x2[(size_t)r0 * 64 + lane];
    ax = fmaf(w0, v0.x, ax); ay = fmaf(w0, v0.y, ay);
  }
  float d = deg[wid];
  float2 xo = x2[(size_t)wid * 64 + lane];
  float rx = sc * fmaf(d, xo.x, -ax);
  float ry = sc * fmaf(d, xo.y, -ay);
  if (z) {  // in-place z==y is safe: own-row read happens before own-row write
    const float2* z2 = (const float2*)z;
    float2 zv = z2[(size_t)wid * 64 + lane];
    rx -= zv.x; ry -= zv.y;
  }
  float2 res; res.x = rx; res.y = ry;
  ((float2*)y)[(size_t)wid * 64 + lane] = res;
}

// ---------- out(+)= x @ W (+ bsum on first call) ; fp32 LDS-tiled ----------
__global__ __launch_bounds__(256) void gemm_kernel(float* __restrict__ out,
                                                   const float* __restrict__ x,
                                                   const float* __restrict__ Wg,
                                                   const float* __restrict__ bsum, int n) {
  __shared__ float Xl[TM * C];   // 32 KB
  __shared__ float Wl[64 * C];   // 32 KB (half of W in k at a time)
  int t = threadIdx.x;
  int row0 = blockIdx.x * TM;
  {
    const float4* X4 = (const float4*)x;
    float4* Xl4 = (float4*)Xl;
#pragma unroll
    for (int i = 0; i < 8; ++i) {
      int idx = t + 256 * i;  // 0..2047
      int r = idx >> 5;
      int c4 = idx & 31;
      int gr = row0 + r;
      float4 v = make_float4(0.f, 0.f, 0.f, 0.f);
      if (gr < n) v = X4[(size_t)gr * 32 + c4];
      Xl4[idx] = v;
    }
  }
  int c0 = (t & 31) * 4;
  int rg = t >> 5;  // 0..7 -> rows rg*8 .. rg*8+7
  float acc[8][4];
#pragma unroll
  for (int i = 0; i < 8; ++i) { acc[i][0] = 0.f; acc[i][1] = 0.f; acc[i][2] = 0.f; acc[i][3] = 0.f; }

  for (int ph = 0; ph < 2; ++ph) {
    __syncthreads();  // X ready (ph0) / phase-(ph-1) W consumers done (ph1)
    {
      const float4* W4 = (const float4*)(Wg + ph * 64 * C);
      float4* Wl4 = (float4*)Wl;
#pragma unroll
      for (int i = 0; i < 8; ++i) Wl4[t + 256 * i] = W4[t + 256 * i];
    }
    __syncthreads();
#pragma unroll 4
    for (int k = 0; k < 64; k += 4) {
      float4 xr[8];
#pragma unroll
      for (int rr = 0; rr < 8; ++rr)
        xr[rr] = *(const float4*)&Xl[(rg * 8 + rr) * C + ph * 64 + k];
#pragma unroll
      for (int kk = 0; kk < 4; ++kk) {
        float4 w = *(const float4*)&Wl[(k + kk) * C + c0];
#pragma unroll
        for (int rr = 0; rr < 8; ++rr) {
          float xv = (kk == 0) ? xr[rr].x : (kk == 1) ? xr[rr].y : (kk == 2) ? xr[rr].z : xr[rr].w;
          acc[rr][0] = fmaf(xv, w.x, acc[rr][0]);
          acc[rr][1] = fmaf(xv, w.y, acc[rr][1]);
          acc[rr][2] = fmaf(xv, w.z, acc[rr][2]);
          acc[rr][3] = fmaf(xv, w.w, acc[rr][3]);
        }
      }
    }
  }
#pragma unroll
  for (int rr = 0; rr < 8; ++rr) {
    int gr = row0 + rg * 8 + rr;
    if (gr < n) {
      float4* o = (float4*)&out[(size_t)gr * C + c0];
      float4 base;
      if (bsum) base = *(const float4*)&bsum[c0];
      else base = *o;
      base.x += acc[rr][0]; base.y += acc[rr][1];
      base.z += acc[rr][2]; base.w += acc[rr][3];
      *o = base;
    }
  }
}

extern "C" void kernel_launch(void* const* d_in, const int* in_sizes, int n_in,
                              void* d_out, int out_size, void* d_ws, size_t ws_size,
                              hipStream_t stream) {
  const float* nodes = (const float*)d_in[0];
  const float* edges = (const float*)d_in[1];
  const int* senders = (const int*)d_in[2];
  const int* receivers = (const int*)d_in[3];
  const float* W = (const float*)d_in[4];
  const float* b_dense = (const float*)d_in[5];
  const float* bias = (const float*)d_in[6];
  float* out = (float*)d_out;
  int n = in_sizes[0] / C;
  int ne = in_sizes[1];

  char* ws = (char*)d_ws;
  size_t off = 0;
  auto alloc = [&](size_t b) { size_t r = off; off += (b + 255) & ~(size_t)255; return r; };
  float* deg = (float*)(ws + alloc((size_t)n * 4));
  int* counts = (int*)(ws + alloc((size_t)n * 4));
  int* cursor = (int*)(ws + alloc((size_t)n * 4));
  int* offsets = (int*)(ws + alloc((size_t)(n + 1) * 4));
  float* csr_w = (float*)(ws + alloc((size_t)ne * 4));
  int* csr_r = (int*)(ws + alloc((size_t)ne * 4));
  unsigned* umax = (unsigned*)(ws + alloc(4));
  float* scalep = (float*)(ws + alloc(4));
  float* bsum = (float*)(ws + alloc(C * 4));
  float* TxA = (float*)(ws + alloc((size_t)n * C * 4));
  float* TxB = (float*)(ws + alloc((size_t)n * C * 4));
  (void)ws_size; (void)n_in; (void)out_size;

  hipMemsetAsync(counts, 0, (size_t)n * 4, stream);
  hipMemsetAsync(cursor, 0, (size_t)n * 4, stream);
  hipMemsetAsync(umax, 0, 4, stream);  // 0 < any real encoding

  bsum_kernel<<<1, C, 0, stream>>>(b_dense, bias, bsum);
  hist_kernel<<<(ne + 255) / 256, 256, 0, stream>>>(senders, ne, counts);
  scan_kernel<<<1, 1024, 0, stream>>>(counts, offsets, n);
  scatter_kernel<<<(ne + 255) / 256, 256, 0, stream>>>(senders, receivers, edges, ne, offsets,
                                                       cursor, csr_w, csr_r);
  deg_kernel<<<(n + 255) / 256, 256, 0, stream>>>(offsets, csr_w, n, deg, umax);
  negedge_max_kernel<<<256, 256, 0, stream>>>(edges, ne, umax);
  scale_kernel<<<1, 1, 0, stream>>>(umax, scalep);

  int gblocks = (n + TM - 1) / TM;
  int mvblocks = (n * 64 + 255) / 256;

  // out = nodes@W0 + (sum_k b_k + bias)
  gemm_kernel<<<gblocks, 256, 0, stream>>>(out, nodes, W + 0 * C * C, bsum, n);
  // Tx1 = L̂ nodes
  matvec_kernel<<<mvblocks, 256, 0, stream>>>(TxA, nodes, nullptr, deg, offsets, csr_w, csr_r,
                                              scalep, 1.0f, n);
  gemm_kernel<<<gblocks, 256, 0, stream>>>(out, TxA, W + 1 * C * C, nullptr, n);
  // Tx2 = 2 L̂ Tx1 - Tx0
  matvec_kernel<<<mvblocks, 256, 0, stream>>>(TxB, TxA, nodes, deg, offsets, csr_w, csr_r,
                                              scalep, 2.0f, n);
  gemm_kernel<<<gblocks, 256, 0, stream>>>(out, TxB, W + 2 * C * C, nullptr, n);
  // Tx3 = 2 L̂ Tx2 - Tx1  (write over Tx1's buffer; z==y in-place is safe)
  matvec_kernel<<<mvblocks, 256, 0, stream>>>(TxA, TxB, TxA, deg, offsets, csr_w, csr_r,
                                              scalep, 2.0f, n);
  gemm_kernel<<<gblocks, 256, 0, stream>>>(out, TxA, W + 3 * C * C, nullptr, n);
  // Tx4
  matvec_kernel<<<mvblocks, 256, 0, stream>>>(TxB, TxA, TxB, deg, offsets, csr_w, csr_r,
                                              scalep, 2.0f, n);
  gemm_kernel<<<gblocks, 256, 0, stream>>>(out, TxB, W + 4 * C * C, nullptr, n);
  // Tx5
  matvec_kernel<<<mvblocks, 256, 0, stream>>>(TxA, TxB, TxA, deg, offsets, csr_w, csr_r,
                                              scalep, 2.0f, n);
  gemm_kernel<<<gblocks, 256, 0, stream>>>(out, TxA, W + 5 * C * C, nullptr, n);
}

// Round 2
// 877.159 us; speedup vs baseline: 1.1073x; 1.1073x over previous
//
#include <hip/hip_runtime.h>

#define C 128
#define KORD 6
#define TM 64

// ---------- monotone float<->uint encoding for atomicMax over floats ----------
__device__ __forceinline__ unsigned enc_f32(float f) {
  unsigned u = __float_as_uint(f);
  return (u & 0x80000000u) ? ~u : (u | 0x80000000u);
}
__device__ __forceinline__ float dec_f32(unsigned u) {
  return (u & 0x80000000u) ? __uint_as_float(u ^ 0x80000000u) : __uint_as_float(~u);
}

// ---------- bias sum: bsum[c] = sum_k b_dense[k][c] + bias[c] ----------
__global__ void bsum_kernel(const float* __restrict__ bd, const float* __restrict__ bias,
                            float* __restrict__ bsum) {
  int c = threadIdx.x;
  float s = bias[c];
#pragma unroll
  for (int k = 0; k < KORD; ++k) s += bd[k * C + c];
  bsum[c] = s;
}

// ---------- CSR build: histogram ----------
__global__ void hist_kernel(const int* __restrict__ senders, int ne, int* __restrict__ counts) {
  int e = blockIdx.x * blockDim.x + threadIdx.x;
  if (e < ne) atomicAdd(&counts[senders[e]], 1);
}

// ---------- multiblock exclusive scan, stage 1: per-1024-chunk scan ----------
__global__ __launch_bounds__(1024) void scan1_kernel(const int* __restrict__ counts,
                                                     int* __restrict__ offsets,
                                                     int* __restrict__ bsums, int n) {
  int t = threadIdx.x;
  int i = blockIdx.x * 1024 + t;
  int lane = t & 63, w = t >> 6;
  int v = (i < n) ? counts[i] : 0;
  int s = v;
#pragma unroll
  for (int d = 1; d < 64; d <<= 1) {
    int o = __shfl_up(s, d, 64);
    if (lane >= d) s += o;
  }
  __shared__ int wsum[16];
  if (lane == 63) wsum[w] = s;
  __syncthreads();
  if (t < 16) {
    int ws = wsum[t];
#pragma unroll
    for (int d = 1; d < 16; d <<= 1) {
      int o = __shfl_up(ws, d, 64);
      if (t >= d) ws += o;
    }
    wsum[t] = ws;  // inclusive wave sums
  }
  __syncthreads();
  int excl = s - v + (w > 0 ? wsum[w - 1] : 0);
  if (i < n) offsets[i] = excl;
  if (t == 1023) bsums[blockIdx.x] = wsum[15];
}

// ---------- stage 2: exclusive scan of block sums (nb <= 1024), total -> offsets[n] ----------
__global__ __launch_bounds__(1024) void scan2_kernel(int* __restrict__ bsums,
                                                     int* __restrict__ offsets, int nb, int n) {
  int t = threadIdx.x;
  int lane = t & 63, w = t >> 6;
  int v = (t < nb) ? bsums[t] : 0;
  int s = v;
#pragma unroll
  for (int d = 1; d < 64; d <<= 1) {
    int o = __shfl_up(s, d, 64);
    if (lane >= d) s += o;
  }
  __shared__ int wsum[16];
  if (lane == 63) wsum[w] = s;
  __syncthreads();
  if (t < 16) {
    int ws = wsum[t];
#pragma unroll
    for (int d = 1; d < 16; d <<= 1) {
      int o = __shfl_up(ws, d, 64);
      if (t >= d) ws += o;
    }
    wsum[t] = ws;
  }
  __syncthreads();
  int excl = s - v + (w > 0 ? wsum[w - 1] : 0);
  if (t < nb) bsums[t] = excl;
  if (t == 0) offsets[n] = wsum[15];  // grand total
}

// ---------- stage 3: add block offsets ----------
__global__ void scan3_kernel(int* __restrict__ offsets, const int* __restrict__ bsums, int n) {
  int i = blockIdx.x * blockDim.x + threadIdx.x;
  if (i < n) offsets[i] += bsums[i >> 10];
}

// ---------- scatter edges into CSR order, packed (weight_bits, receiver) ----------
__global__ void scatter_kernel(const int* __restrict__ senders, const int* __restrict__ receivers,
                               const float* __restrict__ edges, int ne,
                               const int* __restrict__ offsets, int* __restrict__ cursor,
                               int2* __restrict__ csr_wr) {
  int e = blockIdx.x * blockDim.x + threadIdx.x;
  if (e >= ne) return;
  int s = senders[e];
  int p = offsets[s] + atomicAdd(&cursor[s], 1);
  int2 wr;
  wr.x = __float_as_int(edges[e]);
  wr.y = receivers[e];
  csr_wr[p] = wr;
}

// ---------- deg[i] = row sum; fused max-reduce into umax ----------
__global__ void deg_kernel(const int* __restrict__ offsets, const int2* __restrict__ csr_wr,
                           int n, float* __restrict__ deg, unsigned* __restrict__ umax) {
  int i = blockIdx.x * blockDim.x + threadIdx.x;
  float d = 0.f;
  if (i < n) {
    int e0 = offsets[i], e1 = offsets[i + 1];
    for (int e = e0; e < e1; ++e) d += __int_as_float(csr_wr[e].x);
    deg[i] = d;
  }
  float m = (i < n) ? d : 0.f;  // deg >= 0, so 0 filler is safe
#pragma unroll
  for (int off = 32; off > 0; off >>= 1) m = fmaxf(m, __shfl_down(m, off, 64));
  if ((threadIdx.x & 63) == 0) atomicMax(umax, enc_f32(m));
}

// ---------- max over (-edges) ----------
__global__ void negedge_max_kernel(const float* __restrict__ edges, int ne,
                                   unsigned* __restrict__ umax) {
  int i = blockIdx.x * blockDim.x + threadIdx.x;
  float m = -INFINITY;
  for (int e = i; e < ne; e += gridDim.x * blockDim.x) m = fmaxf(m, -edges[e]);
#pragma unroll
  for (int off = 32; off > 0; off >>= 1) m = fmaxf(m, __shfl_down(m, off, 64));
  if ((threadIdx.x & 63) == 0) atomicMax(umax, enc_f32(m));
}

// ---------- scale = 2/lambda_max = 1/max ----------
__global__ void scale_kernel(const unsigned* __restrict__ umax, float* __restrict__ scalep) {
  *scalep = 1.0f / dec_f32(*umax);
}

// ---------- y = coef*scale*(deg*x - A_gather(x)) - z ----------
// One wave per node. Each half-wave (32 lanes, float4/lane = full 128-ch row)
// processes alternating edges; cross-half combine via shfl_xor(32) at the end.
__global__ __launch_bounds__(256) void matvec_kernel(
    float* __restrict__ y, const float* __restrict__ x, const float* __restrict__ z,
    const float* __restrict__ deg, const int* __restrict__ offsets,
    const int2* __restrict__ csr_wr, const float* __restrict__ scalep, float coef, int n) {
  int wid = (blockIdx.x * blockDim.x + threadIdx.x) >> 6;
  int lane = threadIdx.x & 63;
  int sub = lane & 31;
  int half = lane >> 5;
  if (wid >= n) return;
  float sc = scalep[0] * coef;
  int e0 = offsets[wid], e1 = offsets[wid + 1];
  const float4* x4 = (const float4*)x;
  float4 a = make_float4(0.f, 0.f, 0.f, 0.f);
  for (int e = e0 + half; e < e1; e += 2) {
    int2 p = csr_wr[e];
    float w = __int_as_float(p.x);
    float4 v = x4[(size_t)p.y * 32 + sub];
    a.x = fmaf(w, v.x, a.x);
    a.y = fmaf(w, v.y, a.y);
    a.z = fmaf(w, v.z, a.z);
    a.w = fmaf(w, v.w, a.w);
  }
  // combine the two half-wave partials (lane i <-> lane i^32 hold same sub)
  a.x += __shfl_xor(a.x, 32, 64);
  a.y += __shfl_xor(a.y, 32, 64);
  a.z += __shfl_xor(a.z, 32, 64);
  a.w += __shfl_xor(a.w, 32, 64);
  if (half == 0) {
    float d = deg[wid];
    float4 xo = x4[(size_t)wid * 32 + sub];
    float4 r;
    r.x = sc * fmaf(d, xo.x, -a.x);
    r.y = sc * fmaf(d, xo.y, -a.y);
    r.z = sc * fmaf(d, xo.z, -a.z);
    r.w = sc * fmaf(d, xo.w, -a.w);
    if (z) {  // in-place z==y safe: own-row read before own-row write
      float4 zv = ((const float4*)z)[(size_t)wid * 32 + sub];
      r.x -= zv.x; r.y -= zv.y; r.z -= zv.z; r.w -= zv.w;
    }
    ((float4*)y)[(size_t)wid * 32 + sub] = r;
  }
}

// ---------- out(+)= x @ W (+ bsum on first call) ; fp32 LDS-tiled ----------
__global__ __launch_bounds__(256) void gemm_kernel(float* __restrict__ out,
                                                   const float* __restrict__ x,
                                                   const float* __restrict__ Wg,
                                                   const float* __restrict__ bsum, int n) {
  __shared__ float Xl[TM * C];   // 32 KB
  __shared__ float Wl[64 * C];   // 32 KB (half of W in k at a time)
  int t = threadIdx.x;
  int row0 = blockIdx.x * TM;
  {
    const float4* X4 = (const float4*)x;
    float4* Xl4 = (float4*)Xl;
#pragma unroll
    for (int i = 0; i < 8; ++i) {
      int idx = t + 256 * i;  // 0..2047
      int r = idx >> 5;
      int c4 = idx & 31;
      int gr = row0 + r;
      float4 v = make_float4(0.f, 0.f, 0.f, 0.f);
      if (gr < n) v = X4[(size_t)gr * 32 + c4];
      Xl4[idx] = v;
    }
  }
  int c0 = (t & 31) * 4;
  int rg = t >> 5;  // 0..7 -> rows rg*8 .. rg*8+7
  float acc[8][4];
#pragma unroll
  for (int i = 0; i < 8; ++i) { acc[i][0] = 0.f; acc[i][1] = 0.f; acc[i][2] = 0.f; acc[i][3] = 0.f; }

  for (int ph = 0; ph < 2; ++ph) {
    __syncthreads();  // X ready (ph0) / phase-(ph-1) W consumers done (ph1)
    {
      const float4* W4 = (const float4*)(Wg + ph * 64 * C);
      float4* Wl4 = (float4*)Wl;
#pragma unroll
      for (int i = 0; i < 8; ++i) Wl4[t + 256 * i] = W4[t + 256 * i];
    }
    __syncthreads();
#pragma unroll 4
    for (int k = 0; k < 64; k += 4) {
      float4 xr[8];
#pragma unroll
      for (int rr = 0; rr < 8; ++rr)
        xr[rr] = *(const float4*)&Xl[(rg * 8 + rr) * C + ph * 64 + k];
#pragma unroll
      for (int kk = 0; kk < 4; ++kk) {
        float4 w = *(const float4*)&Wl[(k + kk) * C + c0];
#pragma unroll
        for (int rr = 0; rr < 8; ++rr) {
          float xv = (kk == 0) ? xr[rr].x : (kk == 1) ? xr[rr].y : (kk == 2) ? xr[rr].z : xr[rr].w;
          acc[rr][0] = fmaf(xv, w.x, acc[rr][0]);
          acc[rr][1] = fmaf(xv, w.y, acc[rr][1]);
          acc[rr][2] = fmaf(xv, w.z, acc[rr][2]);
          acc[rr][3] = fmaf(xv, w.w, acc[rr][3]);
        }
      }
    }
  }
#pragma unroll
  for (int rr = 0; rr < 8; ++rr) {
    int gr = row0 + rg * 8 + rr;
    if (gr < n) {
      float4* o = (float4*)&out[(size_t)gr * C + c0];
      float4 base;
      if (bsum) base = *(const float4*)&bsum[c0];
      else base = *o;
      base.x += acc[rr][0]; base.y += acc[rr][1];
      base.z += acc[rr][2]; base.w += acc[rr][3];
      *o = base;
    }
  }
}

extern "C" void kernel_launch(void* const* d_in, const int* in_sizes, int n_in,
                              void* d_out, int out_size, void* d_ws, size_t ws_size,
                              hipStream_t stream) {
  const float* nodes = (const float*)d_in[0];
  const float* edges = (const float*)d_in[1];
  const int* senders = (const int*)d_in[2];
  const int* receivers = (const int*)d_in[3];
  const float* W = (const float*)d_in[4];
  const float* b_dense = (const float*)d_in[5];
  const float* bias = (const float*)d_in[6];
  float* out = (float*)d_out;
  int n = in_sizes[0] / C;
  int ne = in_sizes[1];
  int nb = (n + 1023) / 1024;

  char* ws = (char*)d_ws;
  size_t off = 0;
  auto alloc = [&](size_t b) { size_t r = off; off += (b + 255) & ~(size_t)255; return r; };
  float* deg = (float*)(ws + alloc((size_t)n * 4));
  int* counts = (int*)(ws + alloc((size_t)n * 4));
  int* cursor = (int*)(ws + alloc((size_t)n * 4));
  int* offsets = (int*)(ws + alloc((size_t)(n + 1) * 4));
  int* bsums = (int*)(ws + alloc((size_t)nb * 4));
  int2* csr_wr = (int2*)(ws + alloc((size_t)ne * 8));
  unsigned* umax = (unsigned*)(ws + alloc(4));
  float* scalep = (float*)(ws + alloc(4));
  float* bsum = (float*)(ws + alloc(C * 4));
  float* TxA = (float*)(ws + alloc((size_t)n * C * 4));
  float* TxB = (float*)(ws + alloc((size_t)n * C * 4));
  (void)ws_size; (void)n_in; (void)out_size;

  hipMemsetAsync(counts, 0, (size_t)n * 4, stream);
  hipMemsetAsync(cursor, 0, (size_t)n * 4, stream);
  hipMemsetAsync(umax, 0, 4, stream);  // 0 < any real encoding

  bsum_kernel<<<1, C, 0, stream>>>(b_dense, bias, bsum);
  hist_kernel<<<(ne + 255) / 256, 256, 0, stream>>>(senders, ne, counts);
  scan1_kernel<<<nb, 1024, 0, stream>>>(counts, offsets, bsums, n);
  scan2_kernel<<<1, 1024, 0, stream>>>(bsums, offsets, nb, n);
  scan3_kernel<<<(n + 255) / 256, 256, 0, stream>>>(offsets, bsums, n);
  scatter_kernel<<<(ne + 255) / 256, 256, 0, stream>>>(senders, receivers, edges, ne, offsets,
                                                       cursor, csr_wr);
  deg_kernel<<<(n + 255) / 256, 256, 0, stream>>>(offsets, csr_wr, n, deg, umax);
  negedge_max_kernel<<<256, 256, 0, stream>>>(edges, ne, umax);
  scale_kernel<<<1, 1, 0, stream>>>(umax, scalep);

  int gblocks = (n + TM - 1) / TM;
  int mvblocks = (n * 64 + 255) / 256;

  // out = nodes@W0 + (sum_k b_k + bias)
  gemm_kernel<<<gblocks, 256, 0, stream>>>(out, nodes, W + 0 * C * C, bsum, n);
  // Tx1 = L̂ nodes
  matvec_kernel<<<mvblocks, 256, 0, stream>>>(TxA, nodes, nullptr, deg, offsets, csr_wr,
                                              scalep, 1.0f, n);
  gemm_kernel<<<gblocks, 256, 0, stream>>>(out, TxA, W + 1 * C * C, nullptr, n);
  // Tx2 = 2 L̂ Tx1 - Tx0
  matvec_kernel<<<mvblocks, 256, 0, stream>>>(TxB, TxA, nodes, deg, offsets, csr_wr,
                                              scalep, 2.0f, n);
  gemm_kernel<<<gblocks, 256, 0, stream>>>(out, TxB, W + 2 * C * C, nullptr, n);
  // Tx3 = 2 L̂ Tx2 - Tx1  (write over Tx1's buffer; z==y in-place is safe)
  matvec_kernel<<<mvblocks, 256, 0, stream>>>(TxA, TxB, TxA, deg, offsets, csr_wr,
                                              scalep, 2.0f, n);
  gemm_kernel<<<gblocks, 256, 0, stream>>>(out, TxA, W + 3 * C * C, nullptr, n);
  // Tx4
  matvec_kernel<<<mvblocks, 256, 0, stream>>>(TxB, TxA, TxB, deg, offsets, csr_wr,
                                              scalep, 2.0f, n);
  gemm_kernel<<<gblocks, 256, 0, stream>>>(out, TxB, W + 4 * C * C, nullptr, n);
  // Tx5
  matvec_kernel<<<mvblocks, 256, 0, stream>>>(TxA, TxB, TxA, deg, offsets, csr_wr,
                                              scalep, 2.0f, n);
  gemm_kernel<<<gblocks, 256, 0, stream>>>(out, TxA, W + 5 * C * C, nullptr, n);
}

// Round 3
// 618.844 us; speedup vs baseline: 1.5694x; 1.4174x over previous
//
#include <hip/hip_runtime.h>

#define C 128
#define KORD 6
#define KD (KORD * C)  // 768 fused reduction dim

typedef __attribute__((ext_vector_type(8))) short short8;   // 8 bf16
typedef __attribute__((ext_vector_type(4))) float f32x4;

// ---------- fp32 -> bf16 (RNE) ----------
__device__ __forceinline__ short f2bf(float f) {
  unsigned u = __float_as_uint(f);
  unsigned r = (u + 0x7fffu + ((u >> 16) & 1u)) >> 16;
  return (short)r;
}

// ---------- monotone float<->uint encoding for atomicMax over floats ----------
__device__ __forceinline__ unsigned enc_f32(float f) {
  unsigned u = __float_as_uint(f);
  return (u & 0x80000000u) ? ~u : (u | 0x80000000u);
}
__device__ __forceinline__ float dec_f32(unsigned u) {
  return (u & 0x80000000u) ? __uint_as_float(u ^ 0x80000000u) : __uint_as_float(~u);
}

// ---------- bias sum: bsum[c] = sum_k b_dense[k][c] + bias[c] ----------
__global__ void bsum_kernel(const float* __restrict__ bd, const float* __restrict__ bias,
                            float* __restrict__ bsum) {
  int c = threadIdx.x;
  float s = bias[c];
#pragma unroll
  for (int k = 0; k < KORD; ++k) s += bd[k * C + c];
  bsum[c] = s;
}

// ---------- nodes -> bf16 slot 0 of Xb (n x 768) ----------
__global__ void cvt_nodes_kernel(const float* __restrict__ nodes, short* __restrict__ xb, int n) {
  int idx = blockIdx.x * blockDim.x + threadIdx.x;  // n*32
  if (idx >= n * 32) return;
  int row = idx >> 5, c4 = idx & 31;
  float4 v = ((const float4*)nodes)[(size_t)row * 32 + c4];
  short4 o;
  o.x = f2bf(v.x); o.y = f2bf(v.y); o.z = f2bf(v.z); o.w = f2bf(v.w);
  ((short4*)(xb + (size_t)row * KD))[c4] = o;
}

// ---------- W (768x128) -> Wt bf16 (128 x 768) ----------
__global__ void wt_kernel(const float* __restrict__ W, short* __restrict__ Wt) {
  int i = blockIdx.x * blockDim.x + threadIdx.x;  // KD*C
  if (i >= KD * C) return;
  int k = i >> 7, nn = i & 127;
  Wt[(size_t)nn * KD + k] = f2bf(W[i]);
}

// ---------- CSR build: histogram ----------
__global__ void hist_kernel(const int* __restrict__ senders, int ne, int* __restrict__ counts) {
  int e = blockIdx.x * blockDim.x + threadIdx.x;
  if (e < ne) atomicAdd(&counts[senders[e]], 1);
}

// ---------- multiblock exclusive scan, stage 1 ----------
__global__ __launch_bounds__(1024) void scan1_kernel(const int* __restrict__ counts,
                                                     int* __restrict__ offsets,
                                                     int* __restrict__ bsums, int n) {
  int t = threadIdx.x;
  int i = blockIdx.x * 1024 + t;
  int lane = t & 63, w = t >> 6;
  int v = (i < n) ? counts[i] : 0;
  int s = v;
#pragma unroll
  for (int d = 1; d < 64; d <<= 1) {
    int o = __shfl_up(s, d, 64);
    if (lane >= d) s += o;
  }
  __shared__ int wsum[16];
  if (lane == 63) wsum[w] = s;
  __syncthreads();
  if (t < 16) {
    int ws = wsum[t];
#pragma unroll
    for (int d = 1; d < 16; d <<= 1) {
      int o = __shfl_up(ws, d, 64);
      if (t >= d) ws += o;
    }
    wsum[t] = ws;
  }
  __syncthreads();
  int excl = s - v + (w > 0 ? wsum[w - 1] : 0);
  if (i < n) offsets[i] = excl;
  if (t == 1023) bsums[blockIdx.x] = wsum[15];
}

// ---------- stage 2: scan of block sums ----------
__global__ __launch_bounds__(1024) void scan2_kernel(int* __restrict__ bsums,
                                                     int* __restrict__ offsets, int nb, int n) {
  int t = threadIdx.x;
  int lane = t & 63, w = t >> 6;
  int v = (t < nb) ? bsums[t] : 0;
  int s = v;
#pragma unroll
  for (int d = 1; d < 64; d <<= 1) {
    int o = __shfl_up(s, d, 64);
    if (lane >= d) s += o;
  }
  __shared__ int wsum[16];
  if (lane == 63) wsum[w] = s;
  __syncthreads();
  if (t < 16) {
    int ws = wsum[t];
#pragma unroll
    for (int d = 1; d < 16; d <<= 1) {
      int o = __shfl_up(ws, d, 64);
      if (t >= d) ws += o;
    }
    wsum[t] = ws;
  }
  __syncthreads();
  int excl = s - v + (w > 0 ? wsum[w - 1] : 0);
  if (t < nb) bsums[t] = excl;
  if (t == 0) offsets[n] = wsum[15];
}

// ---------- stage 3: add block offsets ----------
__global__ void scan3_kernel(int* __restrict__ offsets, const int* __restrict__ bsums, int n) {
  int i = blockIdx.x * blockDim.x + threadIdx.x;
  if (i < n) offsets[i] += bsums[i >> 10];
}

// ---------- scatter edges into CSR order, packed (weight_bits, receiver) ----------
__global__ void scatter_kernel(const int* __restrict__ senders, const int* __restrict__ receivers,
                               const float* __restrict__ edges, int ne,
                               const int* __restrict__ offsets, int* __restrict__ cursor,
                               int2* __restrict__ csr_wr) {
  int e = blockIdx.x * blockDim.x + threadIdx.x;
  if (e >= ne) return;
  int s = senders[e];
  int p = offsets[s] + atomicAdd(&cursor[s], 1);
  int2 wr;
  wr.x = __float_as_int(edges[e]);
  wr.y = receivers[e];
  csr_wr[p] = wr;
}

// ---------- deg[i] = row sum; fused max-reduce into umax ----------
__global__ void deg_kernel(const int* __restrict__ offsets, const int2* __restrict__ csr_wr,
                           int n, float* __restrict__ deg, unsigned* __restrict__ umax) {
  int i = blockIdx.x * blockDim.x + threadIdx.x;
  float d = 0.f;
  if (i < n) {
    int e0 = offsets[i], e1 = offsets[i + 1];
    for (int e = e0; e < e1; ++e) d += __int_as_float(csr_wr[e].x);
    deg[i] = d;
  }
  float m = (i < n) ? d : 0.f;
#pragma unroll
  for (int off = 32; off > 0; off >>= 1) m = fmaxf(m, __shfl_down(m, off, 64));
  if ((threadIdx.x & 63) == 0) atomicMax(umax, enc_f32(m));
}

// ---------- max over (-edges) ----------
__global__ void negedge_max_kernel(const float* __restrict__ edges, int ne,
                                   unsigned* __restrict__ umax) {
  int i = blockIdx.x * blockDim.x + threadIdx.x;
  float m = -INFINITY;
  for (int e = i; e < ne; e += gridDim.x * blockDim.x) m = fmaxf(m, -edges[e]);
#pragma unroll
  for (int off = 32; off > 0; off >>= 1) m = fmaxf(m, __shfl_down(m, off, 64));
  if ((threadIdx.x & 63) == 0) atomicMax(umax, enc_f32(m));
}

// ---------- scale = 2/lambda_max = 1/max ----------
__global__ void scale_kernel(const unsigned* __restrict__ umax, float* __restrict__ scalep) {
  *scalep = 1.0f / dec_f32(*umax);
}

// ---------- y = coef*scale*(deg*x - A_gather(x)) - z ; also bf16 copy -> xb slot ----------
__global__ __launch_bounds__(256) void matvec_kernel(
    float* __restrict__ y, const float* __restrict__ x, const float* __restrict__ z,
    short* __restrict__ xb_slot,  // &Xb[0*KD + k*128], row stride KD
    const float* __restrict__ deg, const int* __restrict__ offsets,
    const int2* __restrict__ csr_wr, const float* __restrict__ scalep, float coef, int n) {
  int wid = (blockIdx.x * blockDim.x + threadIdx.x) >> 6;
  int lane = threadIdx.x & 63;
  int sub = lane & 31;
  int half = lane >> 5;
  if (wid >= n) return;
  float sc = scalep[0] * coef;
  int e0 = offsets[wid], e1 = offsets[wid + 1];
  const float4* x4 = (const float4*)x;
  float4 a = make_float4(0.f, 0.f, 0.f, 0.f);
  for (int e = e0 + half; e < e1; e += 2) {
    int2 p = csr_wr[e];
    float w = __int_as_float(p.x);
    float4 v = x4[(size_t)p.y * 32 + sub];
    a.x = fmaf(w, v.x, a.x);
    a.y = fmaf(w, v.y, a.y);
    a.z = fmaf(w, v.z, a.z);
    a.w = fmaf(w, v.w, a.w);
  }
  a.x += __shfl_xor(a.x, 32, 64);
  a.y += __shfl_xor(a.y, 32, 64);
  a.z += __shfl_xor(a.z, 32, 64);
  a.w += __shfl_xor(a.w, 32, 64);
  if (half == 0) {
    float d = deg[wid];
    float4 xo = x4[(size_t)wid * 32 + sub];
    float4 r;
    r.x = sc * fmaf(d, xo.x, -a.x);
    r.y = sc * fmaf(d, xo.y, -a.y);
    r.z = sc * fmaf(d, xo.z, -a.z);
    r.w = sc * fmaf(d, xo.w, -a.w);
    if (z) {  // in-place z==y safe: own-row read before own-row write
      float4 zv = ((const float4*)z)[(size_t)wid * 32 + sub];
      r.x -= zv.x; r.y -= zv.y; r.z -= zv.z; r.w -= zv.w;
    }
    ((float4*)y)[(size_t)wid * 32 + sub] = r;
    short4 o;
    o.x = f2bf(r.x); o.y = f2bf(r.y); o.z = f2bf(r.z); o.w = f2bf(r.w);
    ((short4*)(xb_slot + (size_t)wid * KD))[sub] = o;
  }
}

// ---------- fused GEMM: out = Xb (n x 768, bf16) @ W (768x128, via Wt) + bsum ----------
// MFMA 16x16x32 bf16. Wave = 32 rows x 64 cols; block 256 thr = 4 waves = 64 rows x 128 cols.
// A frag: lane holds A[m = lane&15][k = (lane>>4)*8 + j], j=0..7 (16 B contiguous).
// B frag: lane holds B[k = (lane>>4)*8 + j][n = lane&15] -> contiguous in Wt[n][k].
// C/D:    col = lane&15, row = (lane>>4)*4 + reg.
__global__ __launch_bounds__(256) void mfma_gemm_kernel(const short* __restrict__ Xb,
                                                        const short* __restrict__ Wt,
                                                        const float* __restrict__ bsum,
                                                        float* __restrict__ out, int n) {
  int t = threadIdx.x;
  int w = t >> 6, lane = t & 63;
  int m = lane & 15, q = lane >> 4;
  int wr = w >> 1, wc = w & 1;
  int row0 = blockIdx.x * 64 + wr * 32;
  int col0 = wc * 64;

  f32x4 acc[2][4];
#pragma unroll
  for (int i = 0; i < 2; ++i)
#pragma unroll
    for (int j = 0; j < 4; ++j) acc[i][j] = (f32x4){0.f, 0.f, 0.f, 0.f};

  int ra0 = min(row0 + m, n - 1);
  int ra1 = min(row0 + 16 + m, n - 1);
  const short* arow0 = Xb + (size_t)ra0 * KD;
  const short* arow1 = Xb + (size_t)ra1 * KD;

#pragma unroll 2
  for (int k0 = 0; k0 < KD; k0 += 32) {
    int ka = k0 + q * 8;
    short8 a0 = *(const short8*)(arow0 + ka);
    short8 a1 = *(const short8*)(arow1 + ka);
#pragma unroll
    for (int nt = 0; nt < 4; ++nt) {
      short8 b = *(const short8*)(Wt + (size_t)(col0 + nt * 16 + m) * KD + ka);
      acc[0][nt] = __builtin_amdgcn_mfma_f32_16x16x32_bf16(a0, b, acc[0][nt], 0, 0, 0);
      acc[1][nt] = __builtin_amdgcn_mfma_f32_16x16x32_bf16(a1, b, acc[1][nt], 0, 0, 0);
    }
  }

#pragma unroll
  for (int mt = 0; mt < 2; ++mt)
#pragma unroll
    for (int nt = 0; nt < 4; ++nt) {
      int col = col0 + nt * 16 + m;
      float bs = bsum[col];
#pragma unroll
      for (int r = 0; r < 4; ++r) {
        int row = row0 + mt * 16 + q * 4 + r;
        if (row < n) out[(size_t)row * C + col] = acc[mt][nt][r] + bs;
      }
    }
}

extern "C" void kernel_launch(void* const* d_in, const int* in_sizes, int n_in,
                              void* d_out, int out_size, void* d_ws, size_t ws_size,
                              hipStream_t stream) {
  const float* nodes = (const float*)d_in[0];
  const float* edges = (const float*)d_in[1];
  const int* senders = (const int*)d_in[2];
  const int* receivers = (const int*)d_in[3];
  const float* W = (const float*)d_in[4];
  const float* b_dense = (const float*)d_in[5];
  const float* bias = (const float*)d_in[6];
  float* out = (float*)d_out;
  int n = in_sizes[0] / C;
  int ne = in_sizes[1];
  int nb = (n + 1023) / 1024;

  char* ws = (char*)d_ws;
  size_t off = 0;
  auto alloc = [&](size_t b) { size_t r = off; off += (b + 255) & ~(size_t)255; return r; };
  float* deg = (float*)(ws + alloc((size_t)n * 4));
  int* counts = (int*)(ws + alloc((size_t)n * 4));
  int* cursor = (int*)(ws + alloc((size_t)n * 4));
  int* offsets = (int*)(ws + alloc((size_t)(n + 1) * 4));
  int* bsums = (int*)(ws + alloc((size_t)nb * 4));
  int2* csr_wr = (int2*)(ws + alloc((size_t)ne * 8));
  unsigned* umax = (unsigned*)(ws + alloc(4));
  float* scalep = (float*)(ws + alloc(4));
  float* bsum = (float*)(ws + alloc(C * 4));
  float* TxA = (float*)(ws + alloc((size_t)n * C * 4));
  float* TxB = (float*)(ws + alloc((size_t)n * C * 4));
  short* Xb = (short*)(ws + alloc((size_t)n * KD * 2));
  short* Wt = (short*)(ws + alloc((size_t)KD * C * 2));
  (void)ws_size; (void)n_in; (void)out_size;

  hipMemsetAsync(counts, 0, (size_t)n * 4, stream);
  hipMemsetAsync(cursor, 0, (size_t)n * 4, stream);
  hipMemsetAsync(umax, 0, 4, stream);

  bsum_kernel<<<1, C, 0, stream>>>(b_dense, bias, bsum);
  wt_kernel<<<(KD * C + 255) / 256, 256, 0, stream>>>(W, Wt);
  cvt_nodes_kernel<<<(n * 32 + 255) / 256, 256, 0, stream>>>(nodes, Xb, n);
  hist_kernel<<<(ne + 255) / 256, 256, 0, stream>>>(senders, ne, counts);
  scan1_kernel<<<nb, 1024, 0, stream>>>(counts, offsets, bsums, n);
  scan2_kernel<<<1, 1024, 0, stream>>>(bsums, offsets, nb, n);
  scan3_kernel<<<(n + 255) / 256, 256, 0, stream>>>(offsets, bsums, n);
  scatter_kernel<<<(ne + 255) / 256, 256, 0, stream>>>(senders, receivers, edges, ne, offsets,
                                                       cursor, csr_wr);
  deg_kernel<<<(n + 255) / 256, 256, 0, stream>>>(offsets, csr_wr, n, deg, umax);
  negedge_max_kernel<<<256, 256, 0, stream>>>(edges, ne, umax);
  scale_kernel<<<1, 1, 0, stream>>>(umax, scalep);

  int mvblocks = (n * 64 + 255) / 256;

  // Tx1 = L̂ nodes
  matvec_kernel<<<mvblocks, 256, 0, stream>>>(TxA, nodes, nullptr, Xb + 1 * C, deg, offsets,
                                              csr_wr, scalep, 1.0f, n);
  // Tx2 = 2 L̂ Tx1 - Tx0
  matvec_kernel<<<mvblocks, 256, 0, stream>>>(TxB, TxA, nodes, Xb + 2 * C, deg, offsets,
                                              csr_wr, scalep, 2.0f, n);
  // Tx3 = 2 L̂ Tx2 - Tx1 (in-place over TxA; z==y safe)
  matvec_kernel<<<mvblocks, 256, 0, stream>>>(TxA, TxB, TxA, Xb + 3 * C, deg, offsets,
                                              csr_wr, scalep, 2.0f, n);
  // Tx4
  matvec_kernel<<<mvblocks, 256, 0, stream>>>(TxB, TxA, TxB, Xb + 4 * C, deg, offsets,
                                              csr_wr, scalep, 2.0f, n);
  // Tx5
  matvec_kernel<<<mvblocks, 256, 0, stream>>>(TxA, TxB, TxA, Xb + 5 * C, deg, offsets,
                                              csr_wr, scalep, 2.0f, n);

  // out = Xb @ vstack(W) + (sum_k b_k + bias), one fused MFMA GEMM
  mfma_gemm_kernel<<<(n + 63) / 64, 256, 0, stream>>>(Xb, Wt, bsum, out, n);
}

// Round 4
// 576.543 us; speedup vs baseline: 1.6846x; 1.0734x over previous
//
#include <hip/hip_runtime.h>

#define C 128
#define KORD 6
#define KD (KORD * C)  // 768 fused reduction dim

typedef __attribute__((ext_vector_type(8))) short short8;   // 8 bf16
typedef __attribute__((ext_vector_type(4))) float f32x4;

// ---------- fp32 -> bf16 (RNE) ----------
__device__ __forceinline__ short f2bf(float f) {
  unsigned u = __float_as_uint(f);
  unsigned r = (u + 0x7fffu + ((u >> 16) & 1u)) >> 16;
  return (short)r;
}
__device__ __forceinline__ float bf2f(short s) {
  return __uint_as_float(((unsigned)(unsigned short)s) << 16);
}

// ---------- monotone float<->uint encoding for atomicMax over floats ----------
__device__ __forceinline__ unsigned enc_f32(float f) {
  unsigned u = __float_as_uint(f);
  return (u & 0x80000000u) ? ~u : (u | 0x80000000u);
}
__device__ __forceinline__ float dec_f32(unsigned u) {
  return (u & 0x80000000u) ? __uint_as_float(u ^ 0x80000000u) : __uint_as_float(~u);
}

// ---------- bias sum: bsum[c] = sum_k b_dense[k][c] + bias[c] ----------
__global__ void bsum_kernel(const float* __restrict__ bd, const float* __restrict__ bias,
                            float* __restrict__ bsum) {
  int c = threadIdx.x;
  float s = bias[c];
#pragma unroll
  for (int k = 0; k < KORD; ++k) s += bd[k * C + c];
  bsum[c] = s;
}

// ---------- nodes -> bf16 slot 0 of Xb (n x 768) ----------
__global__ void cvt_nodes_kernel(const float* __restrict__ nodes, short* __restrict__ xb, int n) {
  int idx = blockIdx.x * blockDim.x + threadIdx.x;  // n*32
  if (idx >= n * 32) return;
  int row = idx >> 5, c4 = idx & 31;
  float4 v = ((const float4*)nodes)[(size_t)row * 32 + c4];
  short4 o;
  o.x = f2bf(v.x); o.y = f2bf(v.y); o.z = f2bf(v.z); o.w = f2bf(v.w);
  ((short4*)(xb + (size_t)row * KD))[c4] = o;
}

// ---------- W (768x128) -> Wt bf16 (128 x 768) ----------
__global__ void wt_kernel(const float* __restrict__ W, short* __restrict__ Wt) {
  int i = blockIdx.x * blockDim.x + threadIdx.x;  // KD*C
  if (i >= KD * C) return;
  int k = i >> 7, nn = i & 127;
  Wt[(size_t)nn * KD + k] = f2bf(W[i]);
}

// ---------- fused edge pass: counts histogram + float deg + max(-w) ----------
__global__ void hist_deg_kernel(const int* __restrict__ senders, const float* __restrict__ edges,
                                int ne, int* __restrict__ counts, float* __restrict__ degf,
                                unsigned* __restrict__ umax) {
  int e = blockIdx.x * blockDim.x + threadIdx.x;
  float m = -INFINITY;
  if (e < ne) {
    int s = senders[e];
    float w = edges[e];
    atomicAdd(&counts[s], 1);
    atomicAdd(&degf[s], w);
    m = -w;
  }
#pragma unroll
  for (int off = 32; off > 0; off >>= 1) m = fmaxf(m, __shfl_down(m, off, 64));
  if ((threadIdx.x & 63) == 0) atomicMax(umax, enc_f32(m));
}

// ---------- max over deg ----------
__global__ void degmax_kernel(const float* __restrict__ degf, int n, unsigned* __restrict__ umax) {
  int i = blockIdx.x * blockDim.x + threadIdx.x;
  float m = (i < n) ? degf[i] : 0.f;  // deg >= 0
#pragma unroll
  for (int off = 32; off > 0; off >>= 1) m = fmaxf(m, __shfl_down(m, off, 64));
  if ((threadIdx.x & 63) == 0) atomicMax(umax, enc_f32(m));
}

// ---------- multiblock exclusive scan, stage 1 ----------
__global__ __launch_bounds__(1024) void scan1_kernel(const int* __restrict__ counts,
                                                     int* __restrict__ offsets,
                                                     int* __restrict__ bsums, int n) {
  int t = threadIdx.x;
  int i = blockIdx.x * 1024 + t;
  int lane = t & 63, w = t >> 6;
  int v = (i < n) ? counts[i] : 0;
  int s = v;
#pragma unroll
  for (int d = 1; d < 64; d <<= 1) {
    int o = __shfl_up(s, d, 64);
    if (lane >= d) s += o;
  }
  __shared__ int wsum[16];
  if (lane == 63) wsum[w] = s;
  __syncthreads();
  if (t < 16) {
    int ws = wsum[t];
#pragma unroll
    for (int d = 1; d < 16; d <<= 1) {
      int o = __shfl_up(ws, d, 64);
      if (t >= d) ws += o;
    }
    wsum[t] = ws;
  }
  __syncthreads();
  int excl = s - v + (w > 0 ? wsum[w - 1] : 0);
  if (i < n) offsets[i] = excl;
  if (t == 1023) bsums[blockIdx.x] = wsum[15];
}

// ---------- stage 2: scan of block sums ----------
__global__ __launch_bounds__(1024) void scan2_kernel(int* __restrict__ bsums,
                                                     int* __restrict__ offsets, int nb, int n) {
  int t = threadIdx.x;
  int lane = t & 63, w = t >> 6;
  int v = (t < nb) ? bsums[t] : 0;
  int s = v;
#pragma unroll
  for (int d = 1; d < 64; d <<= 1) {
    int o = __shfl_up(s, d, 64);
    if (lane >= d) s += o;
  }
  __shared__ int wsum[16];
  if (lane == 63) wsum[w] = s;
  __syncthreads();
  if (t < 16) {
    int ws = wsum[t];
#pragma unroll
    for (int d = 1; d < 16; d <<= 1) {
      int o = __shfl_up(ws, d, 64);
      if (t >= d) ws += o;
    }
    wsum[t] = ws;
  }
  __syncthreads();
  int excl = s - v + (w > 0 ? wsum[w - 1] : 0);
  if (t < nb) bsums[t] = excl;
  if (t == 0) offsets[n] = wsum[15];
}

// ---------- stage 3: add block offsets ----------
__global__ void scan3_kernel(int* __restrict__ offsets, const int* __restrict__ bsums, int n) {
  int i = blockIdx.x * blockDim.x + threadIdx.x;
  if (i < n) offsets[i] += bsums[i >> 10];
}

// ---------- scatter edges into CSR order; consumes counts as cursor ----------
__global__ void scatter_kernel(const int* __restrict__ senders, const int* __restrict__ receivers,
                               const float* __restrict__ edges, int ne,
                               const int* __restrict__ offsets, int* __restrict__ counts,
                               int2* __restrict__ csr_wr) {
  int e = blockIdx.x * blockDim.x + threadIdx.x;
  if (e >= ne) return;
  int s = senders[e];
  int p = offsets[s] + atomicSub(&counts[s], 1) - 1;
  int2 wr;
  wr.x = __float_as_int(edges[e]);
  wr.y = receivers[e];
  csr_wr[p] = wr;
}

// ---------- scale = 2/lambda_max = 1/max ----------
__global__ void scale_kernel(const unsigned* __restrict__ umax, float* __restrict__ scalep) {
  *scalep = 1.0f / dec_f32(*umax);
}

// ---------- y = coef*scale*(deg*x - A_gather(x_bf16)) - z ; bf16 copy -> xb slot ----------
// One wave per node; each quarter-wave (16 lanes x short8 = full 256 B bf16 row)
// processes every 4th edge; combine via shfl_xor(16), shfl_xor(32).
__global__ __launch_bounds__(256) void matvec_kernel(
    float* __restrict__ y, const float* __restrict__ x, const float* __restrict__ z,
    const short* __restrict__ xg,   // bf16 gather source (row stride KD)
    short* __restrict__ xb_slot,    // bf16 output slot (row stride KD)
    const float* __restrict__ deg, const int* __restrict__ offsets,
    const int2* __restrict__ csr_wr, const float* __restrict__ scalep, float coef, int n) {
  int wid = (blockIdx.x * blockDim.x + threadIdx.x) >> 6;
  int lane = threadIdx.x & 63;
  int sub = lane & 15;
  int quarter = lane >> 4;
  if (wid >= n) return;
  float sc = scalep[0] * coef;
  int e0 = offsets[wid], e1 = offsets[wid + 1];
  float a[8];
#pragma unroll
  for (int j = 0; j < 8; ++j) a[j] = 0.f;
  for (int e = e0 + quarter; e < e1; e += 4) {
    int2 p = csr_wr[e];
    float w = __int_as_float(p.x);
    short8 v = *(const short8*)(xg + (size_t)p.y * KD + sub * 8);
#pragma unroll
    for (int j = 0; j < 8; ++j) a[j] = fmaf(w, bf2f(v[j]), a[j]);
  }
#pragma unroll
  for (int j = 0; j < 8; ++j) {
    a[j] += __shfl_xor(a[j], 16, 64);
    a[j] += __shfl_xor(a[j], 32, 64);
  }
  if (quarter == 0) {
    float d = deg[wid];
    const float4* x4 = (const float4*)x;
    float4 xo0 = x4[(size_t)wid * 32 + sub * 2];
    float4 xo1 = x4[(size_t)wid * 32 + sub * 2 + 1];
    float r[8];
    r[0] = sc * fmaf(d, xo0.x, -a[0]);
    r[1] = sc * fmaf(d, xo0.y, -a[1]);
    r[2] = sc * fmaf(d, xo0.z, -a[2]);
    r[3] = sc * fmaf(d, xo0.w, -a[3]);
    r[4] = sc * fmaf(d, xo1.x, -a[4]);
    r[5] = sc * fmaf(d, xo1.y, -a[5]);
    r[6] = sc * fmaf(d, xo1.z, -a[6]);
    r[7] = sc * fmaf(d, xo1.w, -a[7]);
    if (z) {  // in-place z==y safe: own-row read before own-row write
      const float4* z4 = (const float4*)z;
      float4 z0 = z4[(size_t)wid * 32 + sub * 2];
      float4 z1 = z4[(size_t)wid * 32 + sub * 2 + 1];
      r[0] -= z0.x; r[1] -= z0.y; r[2] -= z0.z; r[3] -= z0.w;
      r[4] -= z1.x; r[5] -= z1.y; r[6] -= z1.z; r[7] -= z1.w;
    }
    float4* y4 = (float4*)y;
    y4[(size_t)wid * 32 + sub * 2] = make_float4(r[0], r[1], r[2], r[3]);
    y4[(size_t)wid * 32 + sub * 2 + 1] = make_float4(r[4], r[5], r[6], r[7]);
    short8 o;
#pragma unroll
    for (int j = 0; j < 8; ++j) o[j] = f2bf(r[j]);
    *(short8*)(xb_slot + (size_t)wid * KD + sub * 8) = o;
  }
}

// ---------- fused GEMM: out = Xb (n x 768 bf16) @ W (768x128) + bsum ----------
// LDS-staged, tile M=64 N=128 BK=64. 4 waves: wave w owns cols w*32..w*32+31, all 64 rows.
// Pad LDS rows by +8 shorts (16 B) so b128 reads hit the 8-phase floor.
#define BK 64
#define LDP (BK + 8)  // padded row stride in shorts
__global__ __launch_bounds__(256) void mfma_gemm_kernel(const short* __restrict__ Xb,
                                                        const short* __restrict__ Wt,
                                                        const float* __restrict__ bsum,
                                                        float* __restrict__ out, int n) {
  __shared__ short Al[64 * LDP];    // 9.2 KB
  __shared__ short Bl[128 * LDP];   // 18.4 KB
  int t = threadIdx.x;
  int w = t >> 6, lane = t & 63;
  int m = lane & 15, q = lane >> 4;
  int row0 = blockIdx.x * 64;
  int c0 = w * 32;

  f32x4 acc[4][2];
#pragma unroll
  for (int i = 0; i < 4; ++i)
#pragma unroll
    for (int j = 0; j < 2; ++j) acc[i][j] = (f32x4){0.f, 0.f, 0.f, 0.f};

  for (int k0 = 0; k0 < KD; k0 += BK) {
    __syncthreads();  // previous chunk's consumers done
    // stage A: 64 rows x 64 k (8 x 16B units per row)
#pragma unroll
    for (int p = 0; p < 2; ++p) {
      int idx = t + 256 * p;         // 0..511
      int r = idx >> 3, u = idx & 7;
      int gr = min(row0 + r, n - 1);
      short8 v = *(const short8*)(Xb + (size_t)gr * KD + k0 + u * 8);
      *(short8*)(Al + r * LDP + u * 8) = v;
    }
    // stage B: 128 cols x 64 k
#pragma unroll
    for (int p = 0; p < 4; ++p) {
      int idx = t + 256 * p;         // 0..1023
      int cc = idx >> 3, u = idx & 7;
      short8 v = *(const short8*)(Wt + (size_t)cc * KD + k0 + u * 8);
      *(short8*)(Bl + cc * LDP + u * 8) = v;
    }
    __syncthreads();
#pragma unroll
    for (int s = 0; s < 2; ++s) {   // two k=32 steps
      int ko = s * 32 + q * 8;
      short8 b0 = *(const short8*)(Bl + (c0 + m) * LDP + ko);
      short8 b1 = *(const short8*)(Bl + (c0 + 16 + m) * LDP + ko);
#pragma unroll
      for (int rt = 0; rt < 4; ++rt) {
        short8 av = *(const short8*)(Al + (rt * 16 + m) * LDP + ko);
        acc[rt][0] = __builtin_amdgcn_mfma_f32_16x16x32_bf16(av, b0, acc[rt][0], 0, 0, 0);
        acc[rt][1] = __builtin_amdgcn_mfma_f32_16x16x32_bf16(av, b1, acc[rt][1], 0, 0, 0);
      }
    }
  }

#pragma unroll
  for (int ct = 0; ct < 2; ++ct) {
    int col = c0 + ct * 16 + m;
    float bs = bsum[col];
#pragma unroll
    for (int rt = 0; rt < 4; ++rt) {
#pragma unroll
      for (int i = 0; i < 4; ++i) {
        int row = row0 + rt * 16 + q * 4 + i;
        if (row < n) out[(size_t)row * C + col] = acc[rt][ct][i] + bs;
      }
    }
  }
}

extern "C" void kernel_launch(void* const* d_in, const int* in_sizes, int n_in,
                              void* d_out, int out_size, void* d_ws, size_t ws_size,
                              hipStream_t stream) {
  const float* nodes = (const float*)d_in[0];
  const float* edges = (const float*)d_in[1];
  const int* senders = (const int*)d_in[2];
  const int* receivers = (const int*)d_in[3];
  const float* W = (const float*)d_in[4];
  const float* b_dense = (const float*)d_in[5];
  const float* bias = (const float*)d_in[6];
  float* out = (float*)d_out;
  int n = in_sizes[0] / C;
  int ne = in_sizes[1];
  int nb = (n + 1023) / 1024;

  char* ws = (char*)d_ws;
  size_t off = 0;
  auto alloc = [&](size_t b) { size_t r = off; off += (b + 255) & ~(size_t)255; return r; };
  float* degf = (float*)(ws + alloc((size_t)n * 4));
  int* counts = (int*)(ws + alloc((size_t)n * 4));
  int* offsets = (int*)(ws + alloc((size_t)(n + 1) * 4));
  int* bsums = (int*)(ws + alloc((size_t)nb * 4));
  int2* csr_wr = (int2*)(ws + alloc((size_t)ne * 8));
  unsigned* umax = (unsigned*)(ws + alloc(4));
  float* scalep = (float*)(ws + alloc(4));
  float* bsum = (float*)(ws + alloc(C * 4));
  float* TxA = (float*)(ws + alloc((size_t)n * C * 4));
  float* TxB = (float*)(ws + alloc((size_t)n * C * 4));
  short* Xb = (short*)(ws + alloc((size_t)n * KD * 2));
  short* Wt = (short*)(ws + alloc((size_t)KD * C * 2));
  (void)ws_size; (void)n_in; (void)out_size;

  hipMemsetAsync(counts, 0, (size_t)n * 4, stream);
  hipMemsetAsync(degf, 0, (size_t)n * 4, stream);
  hipMemsetAsync(umax, 0, 4, stream);

  bsum_kernel<<<1, C, 0, stream>>>(b_dense, bias, bsum);
  wt_kernel<<<(KD * C + 255) / 256, 256, 0, stream>>>(W, Wt);
  cvt_nodes_kernel<<<(n * 32 + 255) / 256, 256, 0, stream>>>(nodes, Xb, n);
  hist_deg_kernel<<<(ne + 255) / 256, 256, 0, stream>>>(senders, edges, ne, counts, degf, umax);
  degmax_kernel<<<(n + 255) / 256, 256, 0, stream>>>(degf, n, umax);
  scan1_kernel<<<nb, 1024, 0, stream>>>(counts, offsets, bsums, n);
  scan2_kernel<<<1, 1024, 0, stream>>>(bsums, offsets, nb, n);
  scan3_kernel<<<(n + 255) / 256, 256, 0, stream>>>(offsets, bsums, n);
  scatter_kernel<<<(ne + 255) / 256, 256, 0, stream>>>(senders, receivers, edges, ne, offsets,
                                                       counts, csr_wr);
  scale_kernel<<<1, 1, 0, stream>>>(umax, scalep);

  int mvblocks = (n * 64 + 255) / 256;

  // Tx1 = L̂ nodes   (gather from bf16 nodes = Xb slot 0)
  matvec_kernel<<<mvblocks, 256, 0, stream>>>(TxA, nodes, nullptr, Xb + 0 * C, Xb + 1 * C,
                                              degf, offsets, csr_wr, scalep, 1.0f, n);
  // Tx2 = 2 L̂ Tx1 - Tx0
  matvec_kernel<<<mvblocks, 256, 0, stream>>>(TxB, TxA, nodes, Xb + 1 * C, Xb + 2 * C,
                                              degf, offsets, csr_wr, scalep, 2.0f, n);
  // Tx3 = 2 L̂ Tx2 - Tx1 (in-place over TxA; z==y safe)
  matvec_kernel<<<mvblocks, 256, 0, stream>>>(TxA, TxB, TxA, Xb + 2 * C, Xb + 3 * C,
                                              degf, offsets, csr_wr, scalep, 2.0f, n);
  // Tx4
  matvec_kernel<<<mvblocks, 256, 0, stream>>>(TxB, TxA, TxB, Xb + 3 * C, Xb + 4 * C,
                                              degf, offsets, csr_wr, scalep, 2.0f, n);
  // Tx5
  matvec_kernel<<<mvblocks, 256, 0, stream>>>(TxA, TxB, TxA, Xb + 4 * C, Xb + 5 * C,
                                              degf, offsets, csr_wr, scalep, 2.0f, n);

  // out = Xb @ vstack(W) + (sum_k b_k + bias), LDS-staged MFMA GEMM
  mfma_gemm_kernel<<<(n + 63) / 64, 256, 0, stream>>>(Xb, Wt, bsum, out, n);
}

// Round 5
// 567.706 us; speedup vs baseline: 1.7108x; 1.0156x over previous
//
#include <hip/hip_runtime.h>

#define C 128
#define KORD 6
#define KD (KORD * C)  // 768 fused reduction dim

typedef __attribute__((ext_vector_type(8))) short short8;   // 8 bf16
typedef __attribute__((ext_vector_type(4))) float f32x4;

// ---------- fp32 -> bf16 (RNE) ----------
__device__ __forceinline__ short f2bf(float f) {
  unsigned u = __float_as_uint(f);
  unsigned r = (u + 0x7fffu + ((u >> 16) & 1u)) >> 16;
  return (short)r;
}
__device__ __forceinline__ float bf2f(short s) {
  return __uint_as_float(((unsigned)(unsigned short)s) << 16);
}

// ---------- monotone float<->uint encoding for atomicMax over floats ----------
__device__ __forceinline__ unsigned enc_f32(float f) {
  unsigned u = __float_as_uint(f);
  return (u & 0x80000000u) ? ~u : (u | 0x80000000u);
}
__device__ __forceinline__ float dec_f32(unsigned u) {
  return (u & 0x80000000u) ? __uint_as_float(u ^ 0x80000000u) : __uint_as_float(~u);
}

// ---------- bias sum: bsum[c] = sum_k b_dense[k][c] + bias[c] ----------
__global__ void bsum_kernel(const float* __restrict__ bd, const float* __restrict__ bias,
                            float* __restrict__ bsum) {
  int c = threadIdx.x;
  float s = bias[c];
#pragma unroll
  for (int k = 0; k < KORD; ++k) s += bd[k * C + c];
  bsum[c] = s;
}

// ---------- nodes -> bf16 slot 0 of Xb (n x 768) ----------
__global__ void cvt_nodes_kernel(const float* __restrict__ nodes, short* __restrict__ xb, int n) {
  int idx = blockIdx.x * blockDim.x + threadIdx.x;  // n*32
  if (idx >= n * 32) return;
  int row = idx >> 5, c4 = idx & 31;
  float4 v = ((const float4*)nodes)[(size_t)row * 32 + c4];
  short4 o;
  o.x = f2bf(v.x); o.y = f2bf(v.y); o.z = f2bf(v.z); o.w = f2bf(v.w);
  ((short4*)(xb + (size_t)row * KD))[c4] = o;
}

// ---------- W (768x128) -> Wt bf16 (128 x 768) ----------
__global__ void wt_kernel(const float* __restrict__ W, short* __restrict__ Wt) {
  int i = blockIdx.x * blockDim.x + threadIdx.x;  // KD*C
  if (i >= KD * C) return;
  int k = i >> 7, nn = i & 127;
  Wt[(size_t)nn * KD + k] = f2bf(W[i]);
}

// ---------- histogram (int atomic, native) + fused max(-w) reduce ----------
__global__ void hist_kernel(const int* __restrict__ senders, const float* __restrict__ edges,
                            int ne, int* __restrict__ counts, unsigned* __restrict__ umax) {
  int e = blockIdx.x * blockDim.x + threadIdx.x;
  float m = -INFINITY;
  if (e < ne) {
    atomicAdd(&counts[senders[e]], 1);
    m = -edges[e];
  }
#pragma unroll
  for (int off = 32; off > 0; off >>= 1) m = fmaxf(m, __shfl_down(m, off, 64));
  if ((threadIdx.x & 63) == 0) atomicMax(umax, enc_f32(m));
}

// ---------- deg[i] = CSR row sum (no float atomics); fused deg-max reduce ----------
__global__ void deg_kernel(const int* __restrict__ offsets, const int2* __restrict__ csr_wr,
                           int n, float* __restrict__ degf, unsigned* __restrict__ umax) {
  int i = blockIdx.x * blockDim.x + threadIdx.x;
  float d = 0.f;
  if (i < n) {
    int e0 = offsets[i], e1 = offsets[i + 1];
    for (int e = e0; e < e1; ++e) d += __int_as_float(csr_wr[e].x);
    degf[i] = d;
  }
  float m = (i < n) ? d : 0.f;  // deg >= 0
#pragma unroll
  for (int off = 32; off > 0; off >>= 1) m = fmaxf(m, __shfl_down(m, off, 64));
  if ((threadIdx.x & 63) == 0) atomicMax(umax, enc_f32(m));
}

// ---------- multiblock exclusive scan, stage 1 ----------
__global__ __launch_bounds__(1024) void scan1_kernel(const int* __restrict__ counts,
                                                     int* __restrict__ offsets,
                                                     int* __restrict__ bsums, int n) {
  int t = threadIdx.x;
  int i = blockIdx.x * 1024 + t;
  int lane = t & 63, w = t >> 6;
  int v = (i < n) ? counts[i] : 0;
  int s = v;
#pragma unroll
  for (int d = 1; d < 64; d <<= 1) {
    int o = __shfl_up(s, d, 64);
    if (lane >= d) s += o;
  }
  __shared__ int wsum[16];
  if (lane == 63) wsum[w] = s;
  __syncthreads();
  if (t < 16) {
    int ws = wsum[t];
#pragma unroll
    for (int d = 1; d < 16; d <<= 1) {
      int o = __shfl_up(ws, d, 64);
      if (t >= d) ws += o;
    }
    wsum[t] = ws;
  }
  __syncthreads();
  int excl = s - v + (w > 0 ? wsum[w - 1] : 0);
  if (i < n) offsets[i] = excl;
  if (t == 1023) bsums[blockIdx.x] = wsum[15];
}

// ---------- stage 2: scan of block sums ----------
__global__ __launch_bounds__(1024) void scan2_kernel(int* __restrict__ bsums,
                                                     int* __restrict__ offsets, int nb, int n) {
  int t = threadIdx.x;
  int lane = t & 63, w = t >> 6;
  int v = (t < nb) ? bsums[t] : 0;
  int s = v;
#pragma unroll
  for (int d = 1; d < 64; d <<= 1) {
    int o = __shfl_up(s, d, 64);
    if (lane >= d) s += o;
  }
  __shared__ int wsum[16];
  if (lane == 63) wsum[w] = s;
  __syncthreads();
  if (t < 16) {
    int ws = wsum[t];
#pragma unroll
    for (int d = 1; d < 16; d <<= 1) {
      int o = __shfl_up(ws, d, 64);
      if (t >= d) ws += o;
    }
    wsum[t] = ws;
  }
  __syncthreads();
  int excl = s - v + (w > 0 ? wsum[w - 1] : 0);
  if (t < nb) bsums[t] = excl;
  if (t == 0) offsets[n] = wsum[15];
}

// ---------- stage 3: add block offsets ----------
__global__ void scan3_kernel(int* __restrict__ offsets, const int* __restrict__ bsums, int n) {
  int i = blockIdx.x * blockDim.x + threadIdx.x;
  if (i < n) offsets[i] += bsums[i >> 10];
}

// ---------- scatter edges into CSR order; consumes counts as cursor ----------
__global__ void scatter_kernel(const int* __restrict__ senders, const int* __restrict__ receivers,
                               const float* __restrict__ edges, int ne,
                               const int* __restrict__ offsets, int* __restrict__ counts,
                               int2* __restrict__ csr_wr) {
  int e = blockIdx.x * blockDim.x + threadIdx.x;
  if (e >= ne) return;
  int s = senders[e];
  int p = offsets[s] + atomicSub(&counts[s], 1) - 1;
  int2 wr;
  wr.x = __float_as_int(edges[e]);
  wr.y = receivers[e];
  csr_wr[p] = wr;
}

// ---------- scale = 2/lambda_max = 1/max ----------
__global__ void scale_kernel(const unsigned* __restrict__ umax, float* __restrict__ scalep) {
  *scalep = 1.0f / dec_f32(*umax);
}

// ---------- y = coef*scale*(deg*x - A_gather(x_bf16)) - z ; bf16 copy -> xb slot ----------
// One wave per node; each quarter-wave (16 lanes x short8 = full 256 B bf16 row)
// processes every 4th edge; combine via shfl_xor(16), shfl_xor(32).
__global__ __launch_bounds__(256) void matvec_kernel(
    float* __restrict__ y, const float* __restrict__ x, const float* __restrict__ z,
    const short* __restrict__ xg,   // bf16 gather source (row stride KD)
    short* __restrict__ xb_slot,    // bf16 output slot (row stride KD)
    const float* __restrict__ deg, const int* __restrict__ offsets,
    const int2* __restrict__ csr_wr, const float* __restrict__ scalep, float coef, int n) {
  int wid = (blockIdx.x * blockDim.x + threadIdx.x) >> 6;
  int lane = threadIdx.x & 63;
  int sub = lane & 15;
  int quarter = lane >> 4;
  if (wid >= n) return;
  float sc = scalep[0] * coef;
  int e0 = offsets[wid], e1 = offsets[wid + 1];
  float a[8];
#pragma unroll
  for (int j = 0; j < 8; ++j) a[j] = 0.f;
  for (int e = e0 + quarter; e < e1; e += 4) {
    int2 p = csr_wr[e];
    float w = __int_as_float(p.x);
    short8 v = *(const short8*)(xg + (size_t)p.y * KD + sub * 8);
#pragma unroll
    for (int j = 0; j < 8; ++j) a[j] = fmaf(w, bf2f(v[j]), a[j]);
  }
#pragma unroll
  for (int j = 0; j < 8; ++j) {
    a[j] += __shfl_xor(a[j], 16, 64);
    a[j] += __shfl_xor(a[j], 32, 64);
  }
  if (quarter == 0) {
    float d = deg[wid];
    const float4* x4 = (const float4*)x;
    float4 xo0 = x4[(size_t)wid * 32 + sub * 2];
    float4 xo1 = x4[(size_t)wid * 32 + sub * 2 + 1];
    float r[8];
    r[0] = sc * fmaf(d, xo0.x, -a[0]);
    r[1] = sc * fmaf(d, xo0.y, -a[1]);
    r[2] = sc * fmaf(d, xo0.z, -a[2]);
    r[3] = sc * fmaf(d, xo0.w, -a[3]);
    r[4] = sc * fmaf(d, xo1.x, -a[4]);
    r[5] = sc * fmaf(d, xo1.y, -a[5]);
    r[6] = sc * fmaf(d, xo1.z, -a[6]);
    r[7] = sc * fmaf(d, xo1.w, -a[7]);
    if (z) {  // in-place z==y safe: own-row read before own-row write
      const float4* z4 = (const float4*)z;
      float4 z0 = z4[(size_t)wid * 32 + sub * 2];
      float4 z1 = z4[(size_t)wid * 32 + sub * 2 + 1];
      r[0] -= z0.x; r[1] -= z0.y; r[2] -= z0.z; r[3] -= z0.w;
      r[4] -= z1.x; r[5] -= z1.y; r[6] -= z1.z; r[7] -= z1.w;
    }
    float4* y4 = (float4*)y;
    y4[(size_t)wid * 32 + sub * 2] = make_float4(r[0], r[1], r[2], r[3]);
    y4[(size_t)wid * 32 + sub * 2 + 1] = make_float4(r[4], r[5], r[6], r[7]);
    short8 o;
#pragma unroll
    for (int j = 0; j < 8; ++j) o[j] = f2bf(r[j]);
    *(short8*)(xb_slot + (size_t)wid * KD + sub * 8) = o;
  }
}

// ---------- fused GEMM: out = Xb (n x 768 bf16) @ W (768x128) + bsum ----------
// LDS-staged, tile M=64 N=128 BK=64. 4 waves: wave w owns cols w*32..w*32+31, all 64 rows.
#define BK 64
#define LDP (BK + 8)  // padded row stride in shorts
__global__ __launch_bounds__(256) void mfma_gemm_kernel(const short* __restrict__ Xb,
                                                        const short* __restrict__ Wt,
                                                        const float* __restrict__ bsum,
                                                        float* __restrict__ out, int n) {
  __shared__ short Al[64 * LDP];    // 9.2 KB
  __shared__ short Bl[128 * LDP];   // 18.4 KB
  int t = threadIdx.x;
  int w = t >> 6, lane = t & 63;
  int m = lane & 15, q = lane >> 4;
  int row0 = blockIdx.x * 64;
  int c0 = w * 32;

  f32x4 acc[4][2];
#pragma unroll
  for (int i = 0; i < 4; ++i)
#pragma unroll
    for (int j = 0; j < 2; ++j) acc[i][j] = (f32x4){0.f, 0.f, 0.f, 0.f};

  for (int k0 = 0; k0 < KD; k0 += BK) {
    __syncthreads();  // previous chunk's consumers done
#pragma unroll
    for (int p = 0; p < 2; ++p) {
      int idx = t + 256 * p;         // 0..511
      int r = idx >> 3, u = idx & 7;
      int gr = min(row0 + r, n - 1);
      short8 v = *(const short8*)(Xb + (size_t)gr * KD + k0 + u * 8);
      *(short8*)(Al + r * LDP + u * 8) = v;
    }
#pragma unroll
    for (int p = 0; p < 4; ++p) {
      int idx = t + 256 * p;         // 0..1023
      int cc = idx >> 3, u = idx & 7;
      short8 v = *(const short8*)(Wt + (size_t)cc * KD + k0 + u * 8);
      *(short8*)(Bl + cc * LDP + u * 8) = v;
    }
    __syncthreads();
#pragma unroll
    for (int s = 0; s < 2; ++s) {   // two k=32 steps
      int ko = s * 32 + q * 8;
      short8 b0 = *(const short8*)(Bl + (c0 + m) * LDP + ko);
      short8 b1 = *(const short8*)(Bl + (c0 + 16 + m) * LDP + ko);
#pragma unroll
      for (int rt = 0; rt < 4; ++rt) {
        short8 av = *(const short8*)(Al + (rt * 16 + m) * LDP + ko);
        acc[rt][0] = __builtin_amdgcn_mfma_f32_16x16x32_bf16(av, b0, acc[rt][0], 0, 0, 0);
        acc[rt][1] = __builtin_amdgcn_mfma_f32_16x16x32_bf16(av, b1, acc[rt][1], 0, 0, 0);
      }
    }
  }

#pragma unroll
  for (int ct = 0; ct < 2; ++ct) {
    int col = c0 + ct * 16 + m;
    float bs = bsum[col];
#pragma unroll
    for (int rt = 0; rt < 4; ++rt) {
#pragma unroll
      for (int i = 0; i < 4; ++i) {
        int row = row0 + rt * 16 + q * 4 + i;
        if (row < n) out[(size_t)row * C + col] = acc[rt][ct][i] + bs;
      }
    }
  }
}

extern "C" void kernel_launch(void* const* d_in, const int* in_sizes, int n_in,
                              void* d_out, int out_size, void* d_ws, size_t ws_size,
                              hipStream_t stream) {
  const float* nodes = (const float*)d_in[0];
  const float* edges = (const float*)d_in[1];
  const int* senders = (const int*)d_in[2];
  const int* receivers = (const int*)d_in[3];
  const float* W = (const float*)d_in[4];
  const float* b_dense = (const float*)d_in[5];
  const float* bias = (const float*)d_in[6];
  float* out = (float*)d_out;
  int n = in_sizes[0] / C;
  int ne = in_sizes[1];
  int nb = (n + 1023) / 1024;

  char* ws = (char*)d_ws;
  size_t off = 0;
  auto alloc = [&](size_t b) { size_t r = off; off += (b + 255) & ~(size_t)255; return r; };
  float* degf = (float*)(ws + alloc((size_t)n * 4));
  int* counts = (int*)(ws + alloc((size_t)n * 4));
  int* offsets = (int*)(ws + alloc((size_t)(n + 1) * 4));
  int* bsums = (int*)(ws + alloc((size_t)nb * 4));
  int2* csr_wr = (int2*)(ws + alloc((size_t)ne * 8));
  unsigned* umax = (unsigned*)(ws + alloc(4));
  float* scalep = (float*)(ws + alloc(4));
  float* bsum = (float*)(ws + alloc(C * 4));
  float* TxA = (float*)(ws + alloc((size_t)n * C * 4));
  float* TxB = (float*)(ws + alloc((size_t)n * C * 4));
  short* Xb = (short*)(ws + alloc((size_t)n * KD * 2));
  short* Wt = (short*)(ws + alloc((size_t)KD * C * 2));
  (void)ws_size; (void)n_in; (void)out_size;

  hipMemsetAsync(counts, 0, (size_t)n * 4, stream);
  hipMemsetAsync(umax, 0, 4, stream);

  bsum_kernel<<<1, C, 0, stream>>>(b_dense, bias, bsum);
  wt_kernel<<<(KD * C + 255) / 256, 256, 0, stream>>>(W, Wt);
  cvt_nodes_kernel<<<(n * 32 + 255) / 256, 256, 0, stream>>>(nodes, Xb, n);
  hist_kernel<<<(ne + 255) / 256, 256, 0, stream>>>(senders, edges, ne, counts, umax);
  scan1_kernel<<<nb, 1024, 0, stream>>>(counts, offsets, bsums, n);
  scan2_kernel<<<1, 1024, 0, stream>>>(bsums, offsets, nb, n);
  scan3_kernel<<<(n + 255) / 256, 256, 0, stream>>>(offsets, bsums, n);
  scatter_kernel<<<(ne + 255) / 256, 256, 0, stream>>>(senders, receivers, edges, ne, offsets,
                                                       counts, csr_wr);
  deg_kernel<<<(n + 255) / 256, 256, 0, stream>>>(offsets, csr_wr, n, degf, umax);
  scale_kernel<<<1, 1, 0, stream>>>(umax, scalep);

  int mvblocks = (n * 64 + 255) / 256;

  // Tx1 = L̂ nodes   (gather from bf16 nodes = Xb slot 0)
  matvec_kernel<<<mvblocks, 256, 0, stream>>>(TxA, nodes, nullptr, Xb + 0 * C, Xb + 1 * C,
                                              degf, offsets, csr_wr, scalep, 1.0f, n);
  // Tx2 = 2 L̂ Tx1 - Tx0
  matvec_kernel<<<mvblocks, 256, 0, stream>>>(TxB, TxA, nodes, Xb + 1 * C, Xb + 2 * C,
                                              degf, offsets, csr_wr, scalep, 2.0f, n);
  // Tx3 = 2 L̂ Tx2 - Tx1 (in-place over TxA; z==y safe)
  matvec_kernel<<<mvblocks, 256, 0, stream>>>(TxA, TxB, TxA, Xb + 2 * C, Xb + 3 * C,
                                              degf, offsets, csr_wr, scalep, 2.0f, n);
  // Tx4
  matvec_kernel<<<mvblocks, 256, 0, stream>>>(TxB, TxA, TxB, Xb + 3 * C, Xb + 4 * C,
                                              degf, offsets, csr_wr, scalep, 2.0f, n);
  // Tx5
  matvec_kernel<<<mvblocks, 256, 0, stream>>>(TxA, TxB, TxA, Xb + 4 * C, Xb + 5 * C,
                                              degf, offsets, csr_wr, scalep, 2.0f, n);

  // out = Xb @ vstack(W) + (sum_k b_k + bias), LDS-staged MFMA GEMM
  mfma_gemm_kernel<<<(n + 63) / 64, 256, 0, stream>>>(Xb, Wt, bsum, out, n);
}

// Round 6
// 387.258 us; speedup vs baseline: 2.5080x; 1.4660x over previous
//
#include <hip/hip_runtime.h>

#define C 128
#define KORD 6
#define KD (KORD * C)  // 768 fused reduction dim
#define EPB 4096       // edges per block in phase-1

typedef __attribute__((ext_vector_type(8))) short short8;   // 8 bf16
typedef __attribute__((ext_vector_type(4))) float f32x4;

// ---------- fp32 -> bf16 (RNE) ----------
__device__ __forceinline__ short f2bf(float f) {
  unsigned u = __float_as_uint(f);
  unsigned r = (u + 0x7fffu + ((u >> 16) & 1u)) >> 16;
  return (short)r;
}
__device__ __forceinline__ float bf2f(short s) {
  return __uint_as_float(((unsigned)(unsigned short)s) << 16);
}

// ---------- monotone float<->uint encoding for atomicMax over floats ----------
__device__ __forceinline__ unsigned enc_f32(float f) {
  unsigned u = __float_as_uint(f);
  return (u & 0x80000000u) ? ~u : (u | 0x80000000u);
}
__device__ __forceinline__ float dec_f32(unsigned u) {
  return (u & 0x80000000u) ? __uint_as_float(u ^ 0x80000000u) : __uint_as_float(~u);
}

// ---------- bias sum: bsum[c] = sum_k b_dense[k][c] + bias[c] ----------
__global__ void bsum_kernel(const float* __restrict__ bd, const float* __restrict__ bias,
                            float* __restrict__ bsum) {
  int c = threadIdx.x;
  float s = bias[c];
#pragma unroll
  for (int k = 0; k < KORD; ++k) s += bd[k * C + c];
  bsum[c] = s;
}

// ---------- nodes -> bf16 slot 0 of Xb (n x 768) ----------
__global__ void cvt_nodes_kernel(const float* __restrict__ nodes, short* __restrict__ xb, int n) {
  int idx = blockIdx.x * blockDim.x + threadIdx.x;  // n*32
  if (idx >= n * 32) return;
  int row = idx >> 5, c4 = idx & 31;
  float4 v = ((const float4*)nodes)[(size_t)row * 32 + c4];
  short4 o;
  o.x = f2bf(v.x); o.y = f2bf(v.y); o.z = f2bf(v.z); o.w = f2bf(v.w);
  ((short4*)(xb + (size_t)row * KD))[c4] = o;
}

// ---------- W (768x128) -> Wt bf16 (128 x 768) ----------
__global__ void wt_kernel(const float* __restrict__ W, short* __restrict__ Wt) {
  int i = blockIdx.x * blockDim.x + threadIdx.x;  // KD*C
  if (i >= KD * C) return;
  int k = i >> 7, nn = i & 127;
  Wt[(size_t)nn * KD + k] = f2bf(W[i]);
}

// ---------- phase 1a: coarse bucket histogram (LDS atomics only) + max(-w) ----------
// hist layout: hist[bucket * NB + block]  (bucket-major for the global scan)
__global__ __launch_bounds__(256) void p1_count_kernel(const int* __restrict__ senders,
                                                       const float* __restrict__ edges, int ne,
                                                       int* __restrict__ hist, int NB,
                                                       unsigned* __restrict__ umax) {
  __shared__ int h[256];
  int t = threadIdx.x;
  h[t] = 0;
  __syncthreads();
  int base = blockIdx.x * EPB;
  int end = min(base + EPB, ne);
  float m = -INFINITY;
  for (int i = base + t; i < end; i += 256) {
    atomicAdd(&h[senders[i] >> 8], 1);
    m = fmaxf(m, -edges[i]);
  }
#pragma unroll
  for (int off = 32; off > 0; off >>= 1) m = fmaxf(m, __shfl_down(m, off, 64));
  if ((t & 63) == 0) atomicMax(umax, enc_f32(m));
  __syncthreads();
  hist[t * NB + blockIdx.x] = h[t];
}

// ---------- multiblock exclusive scan, stage 1 (generic length) ----------
__global__ __launch_bounds__(1024) void scan1_kernel(const int* __restrict__ counts,
                                                     int* __restrict__ offsets,
                                                     int* __restrict__ bsums, int n) {
  int t = threadIdx.x;
  int i = blockIdx.x * 1024 + t;
  int lane = t & 63, w = t >> 6;
  int v = (i < n) ? counts[i] : 0;
  int s = v;
#pragma unroll
  for (int d = 1; d < 64; d <<= 1) {
    int o = __shfl_up(s, d, 64);
    if (lane >= d) s += o;
  }
  __shared__ int wsum[16];
  if (lane == 63) wsum[w] = s;
  __syncthreads();
  if (t < 16) {
    int ws = wsum[t];
#pragma unroll
    for (int d = 1; d < 16; d <<= 1) {
      int o = __shfl_up(ws, d, 64);
      if (t >= d) ws += o;
    }
    wsum[t] = ws;
  }
  __syncthreads();
  int excl = s - v + (w > 0 ? wsum[w - 1] : 0);
  if (i < n) offsets[i] = excl;
  if (t == 1023) bsums[blockIdx.x] = wsum[15];
}

// ---------- stage 2: scan of block sums (nb <= 1024) ----------
__global__ __launch_bounds__(1024) void scan2_kernel(int* __restrict__ bsums, int nb) {
  int t = threadIdx.x;
  int lane = t & 63, w = t >> 6;
  int v = (t < nb) ? bsums[t] : 0;
  int s = v;
#pragma unroll
  for (int d = 1; d < 64; d <<= 1) {
    int o = __shfl_up(s, d, 64);
    if (lane >= d) s += o;
  }
  __shared__ int wsum[16];
  if (lane == 63) wsum[w] = s;
  __syncthreads();
  if (t < 16) {
    int ws = wsum[t];
#pragma unroll
    for (int d = 1; d < 16; d <<= 1) {
      int o = __shfl_up(ws, d, 64);
      if (t >= d) ws += o;
    }
    wsum[t] = ws;
  }
  __syncthreads();
  int excl = s - v + (w > 0 ? wsum[w - 1] : 0);
  if (t < nb) bsums[t] = excl;
}

// ---------- stage 3: add block offsets ----------
__global__ void scan3_kernel(int* __restrict__ offsets, const int* __restrict__ bsums, int n) {
  int i = blockIdx.x * blockDim.x + threadIdx.x;
  if (i < n) offsets[i] += bsums[i >> 10];
}

// ---------- phase 1b: scatter edges into coarse buckets (LDS cursors only) ----------
// bkt[pos] = { w_bits, r | (s_low << 16) }
__global__ __launch_bounds__(256) void p1_scatter_kernel(
    const int* __restrict__ senders, const int* __restrict__ receivers,
    const float* __restrict__ edges, int ne, const int* __restrict__ scanned, int NB,
    int2* __restrict__ bkt) {
  __shared__ int basec[256];  // running cursor, init = this block's base per bucket
  int t = threadIdx.x;
  basec[t] = scanned[t * NB + blockIdx.x];
  __syncthreads();
  int base = blockIdx.x * EPB;
  int end = min(base + EPB, ne);
  for (int i = base + t; i < end; i += 256) {
    int s = senders[i];
    int pos = atomicAdd(&basec[s >> 8], 1);
    int2 rec;
    rec.x = __float_as_int(edges[i]);
    rec.y = receivers[i] | ((s & 255) << 16);
    bkt[pos] = rec;
  }
}

// ---------- phase 2: per-bucket CSR finalize + offsets + deg + deg-max ----------
// Block b owns nodes [b*256, b*256+256). Bucket range from scanned table.
__global__ __launch_bounds__(256) void p2_finalize_kernel(
    const int2* __restrict__ bkt, const int* __restrict__ scanned, int NB, int NBUCK, int ne,
    int n, int2* __restrict__ csr_wr, int* __restrict__ offsets, float* __restrict__ degf,
    unsigned* __restrict__ umax) {
  __shared__ int h[256];
  __shared__ int cur[256];
  __shared__ float dg[256];
  __shared__ int wsum[4];
  __shared__ float wmax[4];
  int t = threadIdx.x;
  int b = blockIdx.x;
  int base = scanned[b * NB];
  int bend = (b == NBUCK - 1) ? ne : scanned[(b + 1) * NB];
  h[t] = 0;
  dg[t] = 0.f;
  __syncthreads();
  // fine histogram over low byte of sender
  for (int i = base + t; i < bend; i += 256) atomicAdd(&h[(bkt[i].y >> 16) & 255], 1);
  __syncthreads();
  // exclusive scan of h[0..255] (4 waves)
  int lane = t & 63, w = t >> 6;
  int v = h[t];
  int s = v;
#pragma unroll
  for (int d = 1; d < 64; d <<= 1) {
    int o = __shfl_up(s, d, 64);
    if (lane >= d) s += o;
  }
  if (lane == 63) wsum[w] = s;
  __syncthreads();
  int carry = 0;
#pragma unroll
  for (int j = 0; j < 4; ++j) carry += (j < w) ? wsum[j] : 0;
  int excl = s - v + carry;
  int node = b * 256 + t;
  if (node < n) offsets[node] = base + excl;
  cur[t] = base + excl;
  __syncthreads();
  // scatter into final CSR + deg accumulate (LDS float atomic = ds_add_f32)
  for (int i = base + t; i < bend; i += 256) {
    int2 rec = bkt[i];
    int bin = (rec.y >> 16) & 255;
    int pos = atomicAdd(&cur[bin], 1);
    int2 outrec;
    outrec.x = rec.x;
    outrec.y = rec.y & 0xFFFF;
    csr_wr[pos] = outrec;
    atomicAdd(&dg[bin], __int_as_float(rec.x));
  }
  __syncthreads();
  float d = dg[t];
  if (node < n) degf[node] = d;
  // block max over deg
  float m = (node < n) ? d : 0.f;
#pragma unroll
  for (int off = 32; off > 0; off >>= 1) m = fmaxf(m, __shfl_down(m, off, 64));
  if (lane == 0) wmax[w] = m;
  __syncthreads();
  if (t == 0) {
    float mm = fmaxf(fmaxf(wmax[0], wmax[1]), fmaxf(wmax[2], wmax[3]));
    atomicMax(umax, enc_f32(mm));
    if (b == NBUCK - 1) offsets[n] = ne;
  }
}

// ---------- scale = 2/lambda_max = 1/max ----------
__global__ void scale_kernel(const unsigned* __restrict__ umax, float* __restrict__ scalep) {
  *scalep = 1.0f / dec_f32(*umax);
}

// ---------- y = coef*scale*(deg*x - A_gather(x_bf16)) - z ; bf16 copy -> xb slot ----------
__global__ __launch_bounds__(256) void matvec_kernel(
    float* __restrict__ y, const float* __restrict__ x, const float* __restrict__ z,
    const short* __restrict__ xg,   // bf16 gather source (row stride KD)
    short* __restrict__ xb_slot,    // bf16 output slot (row stride KD)
    const float* __restrict__ deg, const int* __restrict__ offsets,
    const int2* __restrict__ csr_wr, const float* __restrict__ scalep, float coef, int n) {
  int wid = (blockIdx.x * blockDim.x + threadIdx.x) >> 6;
  int lane = threadIdx.x & 63;
  int sub = lane & 15;
  int quarter = lane >> 4;
  if (wid >= n) return;
  float sc = scalep[0] * coef;
  int e0 = offsets[wid], e1 = offsets[wid + 1];
  float a[8];
#pragma unroll
  for (int j = 0; j < 8; ++j) a[j] = 0.f;
  for (int e = e0 + quarter; e < e1; e += 4) {
    int2 p = csr_wr[e];
    float w = __int_as_float(p.x);
    short8 v = *(const short8*)(xg + (size_t)p.y * KD + sub * 8);
#pragma unroll
    for (int j = 0; j < 8; ++j) a[j] = fmaf(w, bf2f(v[j]), a[j]);
  }
#pragma unroll
  for (int j = 0; j < 8; ++j) {
    a[j] += __shfl_xor(a[j], 16, 64);
    a[j] += __shfl_xor(a[j], 32, 64);
  }
  if (quarter == 0) {
    float d = deg[wid];
    const float4* x4 = (const float4*)x;
    float4 xo0 = x4[(size_t)wid * 32 + sub * 2];
    float4 xo1 = x4[(size_t)wid * 32 + sub * 2 + 1];
    float r[8];
    r[0] = sc * fmaf(d, xo0.x, -a[0]);
    r[1] = sc * fmaf(d, xo0.y, -a[1]);
    r[2] = sc * fmaf(d, xo0.z, -a[2]);
    r[3] = sc * fmaf(d, xo0.w, -a[3]);
    r[4] = sc * fmaf(d, xo1.x, -a[4]);
    r[5] = sc * fmaf(d, xo1.y, -a[5]);
    r[6] = sc * fmaf(d, xo1.z, -a[6]);
    r[7] = sc * fmaf(d, xo1.w, -a[7]);
    if (z) {  // in-place z==y safe: own-row read before own-row write
      const float4* z4 = (const float4*)z;
      float4 z0 = z4[(size_t)wid * 32 + sub * 2];
      float4 z1 = z4[(size_t)wid * 32 + sub * 2 + 1];
      r[0] -= z0.x; r[1] -= z0.y; r[2] -= z0.z; r[3] -= z0.w;
      r[4] -= z1.x; r[5] -= z1.y; r[6] -= z1.z; r[7] -= z1.w;
    }
    float4* y4 = (float4*)y;
    y4[(size_t)wid * 32 + sub * 2] = make_float4(r[0], r[1], r[2], r[3]);
    y4[(size_t)wid * 32 + sub * 2 + 1] = make_float4(r[4], r[5], r[6], r[7]);
    short8 o;
#pragma unroll
    for (int j = 0; j < 8; ++j) o[j] = f2bf(r[j]);
    *(short8*)(xb_slot + (size_t)wid * KD + sub * 8) = o;
  }
}

// ---------- fused GEMM: out = Xb (n x 768 bf16) @ W (768x128) + bsum ----------
#define BK 64
#define LDP (BK + 8)  // padded row stride in shorts
__global__ __launch_bounds__(256) void mfma_gemm_kernel(const short* __restrict__ Xb,
                                                        const short* __restrict__ Wt,
                                                        const float* __restrict__ bsum,
                                                        float* __restrict__ out, int n) {
  __shared__ short Al[64 * LDP];
  __shared__ short Bl[128 * LDP];
  int t = threadIdx.x;
  int w = t >> 6, lane = t & 63;
  int m = lane & 15, q = lane >> 4;
  int row0 = blockIdx.x * 64;
  int c0 = w * 32;

  f32x4 acc[4][2];
#pragma unroll
  for (int i = 0; i < 4; ++i)
#pragma unroll
    for (int j = 0; j < 2; ++j) acc[i][j] = (f32x4){0.f, 0.f, 0.f, 0.f};

  for (int k0 = 0; k0 < KD; k0 += BK) {
    __syncthreads();
#pragma unroll
    for (int p = 0; p < 2; ++p) {
      int idx = t + 256 * p;
      int r = idx >> 3, u = idx & 7;
      int gr = min(row0 + r, n - 1);
      short8 v = *(const short8*)(Xb + (size_t)gr * KD + k0 + u * 8);
      *(short8*)(Al + r * LDP + u * 8) = v;
    }
#pragma unroll
    for (int p = 0; p < 4; ++p) {
      int idx = t + 256 * p;
      int cc = idx >> 3, u = idx & 7;
      short8 v = *(const short8*)(Wt + (size_t)cc * KD + k0 + u * 8);
      *(short8*)(Bl + cc * LDP + u * 8) = v;
    }
    __syncthreads();
#pragma unroll
    for (int s = 0; s < 2; ++s) {
      int ko = s * 32 + q * 8;
      short8 b0 = *(const short8*)(Bl + (c0 + m) * LDP + ko);
      short8 b1 = *(const short8*)(Bl + (c0 + 16 + m) * LDP + ko);
#pragma unroll
      for (int rt = 0; rt < 4; ++rt) {
        short8 av = *(const short8*)(Al + (rt * 16 + m) * LDP + ko);
        acc[rt][0] = __builtin_amdgcn_mfma_f32_16x16x32_bf16(av, b0, acc[rt][0], 0, 0, 0);
        acc[rt][1] = __builtin_amdgcn_mfma_f32_16x16x32_bf16(av, b1, acc[rt][1], 0, 0, 0);
      }
    }
  }

#pragma unroll
  for (int ct = 0; ct < 2; ++ct) {
    int col = c0 + ct * 16 + m;
    float bs = bsum[col];
#pragma unroll
    for (int rt = 0; rt < 4; ++rt) {
#pragma unroll
      for (int i = 0; i < 4; ++i) {
        int row = row0 + rt * 16 + q * 4 + i;
        if (row < n) out[(size_t)row * C + col] = acc[rt][ct][i] + bs;
      }
    }
  }
}

extern "C" void kernel_launch(void* const* d_in, const int* in_sizes, int n_in,
                              void* d_out, int out_size, void* d_ws, size_t ws_size,
                              hipStream_t stream) {
  const float* nodes = (const float*)d_in[0];
  const float* edges = (const float*)d_in[1];
  const int* senders = (const int*)d_in[2];
  const int* receivers = (const int*)d_in[3];
  const float* W = (const float*)d_in[4];
  const float* b_dense = (const float*)d_in[5];
  const float* bias = (const float*)d_in[6];
  float* out = (float*)d_out;
  int n = in_sizes[0] / C;
  int ne = in_sizes[1];
  int NB = (ne + EPB - 1) / EPB;          // phase-1 blocks
  int NBUCK = (n + 255) >> 8;             // coarse buckets (sender>>8)
  int M = 256 * NB;                       // scan table length
  int nb2 = (M + 1023) / 1024;

  char* ws = (char*)d_ws;
  size_t off = 0;
  auto alloc = [&](size_t b) { size_t r = off; off += (b + 255) & ~(size_t)255; return r; };
  float* degf = (float*)(ws + alloc((size_t)n * 4));
  int* offsets = (int*)(ws + alloc((size_t)(n + 1) * 4));
  int* hist = (int*)(ws + alloc((size_t)M * 4));
  int* bsums = (int*)(ws + alloc((size_t)nb2 * 4));
  int2* bkt = (int2*)(ws + alloc((size_t)ne * 8));
  int2* csr_wr = (int2*)(ws + alloc((size_t)ne * 8));
  unsigned* umax = (unsigned*)(ws + alloc(4));
  float* scalep = (float*)(ws + alloc(4));
  float* bsum = (float*)(ws + alloc(C * 4));
  float* TxA = (float*)(ws + alloc((size_t)n * C * 4));
  float* TxB = (float*)(ws + alloc((size_t)n * C * 4));
  short* Xb = (short*)(ws + alloc((size_t)n * KD * 2));
  short* Wt = (short*)(ws + alloc((size_t)KD * C * 2));
  (void)ws_size; (void)n_in; (void)out_size;

  hipMemsetAsync(umax, 0, 4, stream);

  bsum_kernel<<<1, C, 0, stream>>>(b_dense, bias, bsum);
  wt_kernel<<<(KD * C + 255) / 256, 256, 0, stream>>>(W, Wt);
  cvt_nodes_kernel<<<(n * 32 + 255) / 256, 256, 0, stream>>>(nodes, Xb, n);

  // CSR build — no global atomics (LDS atomics + scans only)
  p1_count_kernel<<<NB, 256, 0, stream>>>(senders, edges, ne, hist, NB, umax);
  scan1_kernel<<<nb2, 1024, 0, stream>>>(hist, hist, bsums, M);
  scan2_kernel<<<1, 1024, 0, stream>>>(bsums, nb2);
  scan3_kernel<<<(M + 255) / 256, 256, 0, stream>>>(hist, bsums, M);
  p1_scatter_kernel<<<NB, 256, 0, stream>>>(senders, receivers, edges, ne, hist, NB, bkt);
  p2_finalize_kernel<<<NBUCK, 256, 0, stream>>>(bkt, hist, NB, NBUCK, ne, n, csr_wr, offsets,
                                                degf, umax);
  scale_kernel<<<1, 1, 0, stream>>>(umax, scalep);

  int mvblocks = (n * 64 + 255) / 256;

  // Tx1 = L̂ nodes   (gather from bf16 nodes = Xb slot 0)
  matvec_kernel<<<mvblocks, 256, 0, stream>>>(TxA, nodes, nullptr, Xb + 0 * C, Xb + 1 * C,
                                              degf, offsets, csr_wr, scalep, 1.0f, n);
  // Tx2 = 2 L̂ Tx1 - Tx0
  matvec_kernel<<<mvblocks, 256, 0, stream>>>(TxB, TxA, nodes, Xb + 1 * C, Xb + 2 * C,
                                              degf, offsets, csr_wr, scalep, 2.0f, n);
  // Tx3 = 2 L̂ Tx2 - Tx1 (in-place over TxA; z==y safe)
  matvec_kernel<<<mvblocks, 256, 0, stream>>>(TxA, TxB, TxA, Xb + 2 * C, Xb + 3 * C,
                                              degf, offsets, csr_wr, scalep, 2.0f, n);
  // Tx4
  matvec_kernel<<<mvblocks, 256, 0, stream>>>(TxB, TxA, TxB, Xb + 3 * C, Xb + 4 * C,
                                              degf, offsets, csr_wr, scalep, 2.0f, n);
  // Tx5
  matvec_kernel<<<mvblocks, 256, 0, stream>>>(TxA, TxB, TxA, Xb + 4 * C, Xb + 5 * C,
                                              degf, offsets, csr_wr, scalep, 2.0f, n);

  // out = Xb @ vstack(W) + (sum_k b_k + bias), LDS-staged MFMA GEMM
  mfma_gemm_kernel<<<(n + 63) / 64, 256, 0, stream>>>(Xb, Wt, bsum, out, n);
}

// Round 7
// 364.826 us; speedup vs baseline: 2.6622x; 1.0615x over previous
//
#include <hip/hip_runtime.h>

#define C 128
#define KORD 6
#define KD (KORD * C)  // 768 fused reduction dim
#define EPB 4096       // edges per block in phase-1

typedef __attribute__((ext_vector_type(8))) short short8;   // 8 bf16
typedef __attribute__((ext_vector_type(4))) float f32x4;

// ---------- fp32 -> bf16 (RNE) ----------
__device__ __forceinline__ short f2bf(float f) {
  unsigned u = __float_as_uint(f);
  unsigned r = (u + 0x7fffu + ((u >> 16) & 1u)) >> 16;
  return (short)r;
}
__device__ __forceinline__ float bf2f(short s) {
  return __uint_as_float(((unsigned)(unsigned short)s) << 16);
}

// ---------- monotone float<->uint encoding for atomicMax over floats ----------
__device__ __forceinline__ unsigned enc_f32(float f) {
  unsigned u = __float_as_uint(f);
  return (u & 0x80000000u) ? ~u : (u | 0x80000000u);
}
__device__ __forceinline__ float dec_f32(unsigned u) {
  return (u & 0x80000000u) ? __uint_as_float(u ^ 0x80000000u) : __uint_as_float(~u);
}

// ---------- fused: bsum[c] = sum_k b_dense[k][c] + bias[c]  AND  Wt transpose ----------
// grid: (KD*C + C)/256 blocks; first C threads of block 0 do bsum.
__global__ void prep_kernel(const float* __restrict__ W, const float* __restrict__ bd,
                            const float* __restrict__ bias, short* __restrict__ Wt,
                            float* __restrict__ bsum) {
  int i = blockIdx.x * blockDim.x + threadIdx.x;
  if (i < KD * C) {
    int k = i >> 7, nn = i & 127;
    Wt[(size_t)nn * KD + k] = f2bf(W[i]);
  }
  if (i < C) {
    float s = bias[i];
#pragma unroll
    for (int k = 0; k < KORD; ++k) s += bd[k * C + i];
    bsum[i] = s;
  }
}

// ---------- nodes -> bf16 slot 0 of Xb (n x 768) ----------
__global__ void cvt_nodes_kernel(const float* __restrict__ nodes, short* __restrict__ xb, int n) {
  int idx = blockIdx.x * blockDim.x + threadIdx.x;  // n*32
  if (idx >= n * 32) return;
  int row = idx >> 5, c4 = idx & 31;
  float4 v = ((const float4*)nodes)[(size_t)row * 32 + c4];
  short4 o;
  o.x = f2bf(v.x); o.y = f2bf(v.y); o.z = f2bf(v.z); o.w = f2bf(v.w);
  ((short4*)(xb + (size_t)row * KD))[c4] = o;
}

// ---------- phase 1a: coarse bucket histogram (LDS atomics only) + max(-w) ----------
__global__ __launch_bounds__(256) void p1_count_kernel(const int* __restrict__ senders,
                                                       const float* __restrict__ edges, int ne,
                                                       int* __restrict__ hist, int NB,
                                                       unsigned* __restrict__ umax) {
  __shared__ int h[256];
  int t = threadIdx.x;
  h[t] = 0;
  __syncthreads();
  int base = blockIdx.x * EPB;
  int end = min(base + EPB, ne);
  float m = -INFINITY;
  for (int i = base + t; i < end; i += 256) {
    atomicAdd(&h[senders[i] >> 8], 1);
    m = fmaxf(m, -edges[i]);
  }
#pragma unroll
  for (int off = 32; off > 0; off >>= 1) m = fmaxf(m, __shfl_down(m, off, 64));
  if ((t & 63) == 0) atomicMax(umax, enc_f32(m));
  __syncthreads();
  hist[t * NB + blockIdx.x] = h[t];
}

// ---------- multiblock exclusive scan, stage 1 ----------
__global__ __launch_bounds__(1024) void scan1_kernel(const int* __restrict__ counts,
                                                     int* __restrict__ offsets,
                                                     int* __restrict__ bsums, int n) {
  int t = threadIdx.x;
  int i = blockIdx.x * 1024 + t;
  int lane = t & 63, w = t >> 6;
  int v = (i < n) ? counts[i] : 0;
  int s = v;
#pragma unroll
  for (int d = 1; d < 64; d <<= 1) {
    int o = __shfl_up(s, d, 64);
    if (lane >= d) s += o;
  }
  __shared__ int wsum[16];
  if (lane == 63) wsum[w] = s;
  __syncthreads();
  if (t < 16) {
    int ws = wsum[t];
#pragma unroll
    for (int d = 1; d < 16; d <<= 1) {
      int o = __shfl_up(ws, d, 64);
      if (t >= d) ws += o;
    }
    wsum[t] = ws;
  }
  __syncthreads();
  int excl = s - v + (w > 0 ? wsum[w - 1] : 0);
  if (i < n) offsets[i] = excl;
  if (t == 1023) bsums[blockIdx.x] = wsum[15];
}

// ---------- stage 2: scan of block sums (nb <= 1024) ----------
__global__ __launch_bounds__(1024) void scan2_kernel(int* __restrict__ bsums, int nb) {
  int t = threadIdx.x;
  int lane = t & 63, w = t >> 6;
  int v = (t < nb) ? bsums[t] : 0;
  int s = v;
#pragma unroll
  for (int d = 1; d < 64; d <<= 1) {
    int o = __shfl_up(s, d, 64);
    if (lane >= d) s += o;
  }
  __shared__ int wsum[16];
  if (lane == 63) wsum[w] = s;
  __syncthreads();
  if (t < 16) {
    int ws = wsum[t];
#pragma unroll
    for (int d = 1; d < 16; d <<= 1) {
      int o = __shfl_up(ws, d, 64);
      if (t >= d) ws += o;
    }
    wsum[t] = ws;
  }
  __syncthreads();
  int excl = s - v + (w > 0 ? wsum[w - 1] : 0);
  if (t < nb) bsums[t] = excl;
}

// ---------- stage 3: add block offsets ----------
__global__ void scan3_kernel(int* __restrict__ offsets, const int* __restrict__ bsums, int n) {
  int i = blockIdx.x * blockDim.x + threadIdx.x;
  if (i < n) offsets[i] += bsums[i >> 10];
}

// ---------- phase 1b: scatter edges into coarse buckets (LDS cursors only) ----------
__global__ __launch_bounds__(256) void p1_scatter_kernel(
    const int* __restrict__ senders, const int* __restrict__ receivers,
    const float* __restrict__ edges, int ne, const int* __restrict__ scanned, int NB,
    int2* __restrict__ bkt) {
  __shared__ int basec[256];
  int t = threadIdx.x;
  basec[t] = scanned[t * NB + blockIdx.x];
  __syncthreads();
  int base = blockIdx.x * EPB;
  int end = min(base + EPB, ne);
  for (int i = base + t; i < end; i += 256) {
    int s = senders[i];
    int pos = atomicAdd(&basec[s >> 8], 1);
    int2 rec;
    rec.x = __float_as_int(edges[i]);
    rec.y = receivers[i] | ((s & 255) << 16);
    bkt[pos] = rec;
  }
}

// ---------- phase 2: per-bucket CSR finalize + offsets + deg + deg-max ----------
__global__ __launch_bounds__(256) void p2_finalize_kernel(
    const int2* __restrict__ bkt, const int* __restrict__ scanned, int NB, int NBUCK, int ne,
    int n, int2* __restrict__ csr_wr, int* __restrict__ offsets, float* __restrict__ degf,
    unsigned* __restrict__ umax) {
  __shared__ int h[256];
  __shared__ int cur[256];
  __shared__ float dg[256];
  __shared__ int wsum[4];
  __shared__ float wmax[4];
  int t = threadIdx.x;
  int b = blockIdx.x;
  int base = scanned[b * NB];
  int bend = (b == NBUCK - 1) ? ne : scanned[(b + 1) * NB];
  h[t] = 0;
  dg[t] = 0.f;
  __syncthreads();
  for (int i = base + t; i < bend; i += 256) atomicAdd(&h[(bkt[i].y >> 16) & 255], 1);
  __syncthreads();
  int lane = t & 63, w = t >> 6;
  int v = h[t];
  int s = v;
#pragma unroll
  for (int d = 1; d < 64; d <<= 1) {
    int o = __shfl_up(s, d, 64);
    if (lane >= d) s += o;
  }
  if (lane == 63) wsum[w] = s;
  __syncthreads();
  int carry = 0;
#pragma unroll
  for (int j = 0; j < 4; ++j) carry += (j < w) ? wsum[j] : 0;
  int excl = s - v + carry;
  int node = b * 256 + t;
  if (node < n) offsets[node] = base + excl;
  cur[t] = base + excl;
  __syncthreads();
  for (int i = base + t; i < bend; i += 256) {
    int2 rec = bkt[i];
    int bin = (rec.y >> 16) & 255;
    int pos = atomicAdd(&cur[bin], 1);
    int2 outrec;
    outrec.x = rec.x;
    outrec.y = rec.y & 0xFFFF;
    csr_wr[pos] = outrec;
    atomicAdd(&dg[bin], __int_as_float(rec.x));
  }
  __syncthreads();
  float d = dg[t];
  if (node < n) degf[node] = d;
  float m = (node < n) ? d : 0.f;
#pragma unroll
  for (int off = 32; off > 0; off >>= 1) m = fmaxf(m, __shfl_down(m, off, 64));
  if (lane == 0) wmax[w] = m;
  __syncthreads();
  if (t == 0) {
    float mm = fmaxf(fmaxf(wmax[0], wmax[1]), fmaxf(wmax[2], wmax[3]));
    atomicMax(umax, enc_f32(mm));
    if (b == NBUCK - 1) offsets[n] = ne;
  }
}

// ---------- scale = 2/lambda_max = 1/max ----------
__global__ void scale_kernel(const unsigned* __restrict__ umax, float* __restrict__ scalep) {
  *scalep = 1.0f / dec_f32(*umax);
}

// ---------- Tx_k = coef*scale*(deg*x - A x) - z, all state bf16 in Xb slots ----------
// x = slot k-1 (gather + own-row diagonal), z = slot k-2 (null for k=1), out = slot k.
// One wave per node; quarter-wave (16 lanes x short8 = 256 B row) per edge; fp32 accum.
__global__ __launch_bounds__(256) void matvec_kernel(
    const short* __restrict__ xg,   // gather/diag source slot (row stride KD)
    const short* __restrict__ zg,   // z slot or nullptr
    short* __restrict__ yg,         // output slot
    const float* __restrict__ deg, const int* __restrict__ offsets,
    const int2* __restrict__ csr_wr, const float* __restrict__ scalep, float coef, int n) {
  int wid = (blockIdx.x * blockDim.x + threadIdx.x) >> 6;
  int lane = threadIdx.x & 63;
  int sub = lane & 15;
  int quarter = lane >> 4;
  if (wid >= n) return;
  float sc = scalep[0] * coef;
  int e0 = offsets[wid], e1 = offsets[wid + 1];
  float a[8];
#pragma unroll
  for (int j = 0; j < 8; ++j) a[j] = 0.f;
  for (int e = e0 + quarter; e < e1; e += 4) {
    int2 p = csr_wr[e];
    float w = __int_as_float(p.x);
    short8 v = *(const short8*)(xg + (size_t)p.y * KD + sub * 8);
#pragma unroll
    for (int j = 0; j < 8; ++j) a[j] = fmaf(w, bf2f(v[j]), a[j]);
  }
#pragma unroll
  for (int j = 0; j < 8; ++j) {
    a[j] += __shfl_xor(a[j], 16, 64);
    a[j] += __shfl_xor(a[j], 32, 64);
  }
  if (quarter == 0) {
    float d = deg[wid];
    short8 xo = *(const short8*)(xg + (size_t)wid * KD + sub * 8);
    float r[8];
#pragma unroll
    for (int j = 0; j < 8; ++j) r[j] = sc * fmaf(d, bf2f(xo[j]), -a[j]);
    if (zg) {
      short8 zv = *(const short8*)(zg + (size_t)wid * KD + sub * 8);
#pragma unroll
      for (int j = 0; j < 8; ++j) r[j] -= bf2f(zv[j]);
    }
    short8 o;
#pragma unroll
    for (int j = 0; j < 8; ++j) o[j] = f2bf(r[j]);
    *(short8*)(yg + (size_t)wid * KD + sub * 8) = o;
  }
}

// ---------- fused GEMM: out = Xb (n x 768 bf16) @ W (768x128) + bsum ----------
#define BK 64
#define LDP (BK + 8)  // padded row stride in shorts
__global__ __launch_bounds__(256) void mfma_gemm_kernel(const short* __restrict__ Xb,
                                                        const short* __restrict__ Wt,
                                                        const float* __restrict__ bsum,
                                                        float* __restrict__ out, int n) {
  __shared__ short Al[64 * LDP];
  __shared__ short Bl[128 * LDP];
  int t = threadIdx.x;
  int w = t >> 6, lane = t & 63;
  int m = lane & 15, q = lane >> 4;
  int row0 = blockIdx.x * 64;
  int c0 = w * 32;

  f32x4 acc[4][2];
#pragma unroll
  for (int i = 0; i < 4; ++i)
#pragma unroll
    for (int j = 0; j < 2; ++j) acc[i][j] = (f32x4){0.f, 0.f, 0.f, 0.f};

  for (int k0 = 0; k0 < KD; k0 += BK) {
    __syncthreads();
#pragma unroll
    for (int p = 0; p < 2; ++p) {
      int idx = t + 256 * p;
      int r = idx >> 3, u = idx & 7;
      int gr = min(row0 + r, n - 1);
      short8 v = *(const short8*)(Xb + (size_t)gr * KD + k0 + u * 8);
      *(short8*)(Al + r * LDP + u * 8) = v;
    }
#pragma unroll
    for (int p = 0; p < 4; ++p) {
      int idx = t + 256 * p;
      int cc = idx >> 3, u = idx & 7;
      short8 v = *(const short8*)(Wt + (size_t)cc * KD + k0 + u * 8);
      *(short8*)(Bl + cc * LDP + u * 8) = v;
    }
    __syncthreads();
#pragma unroll
    for (int s = 0; s < 2; ++s) {
      int ko = s * 32 + q * 8;
      short8 b0 = *(const short8*)(Bl + (c0 + m) * LDP + ko);
      short8 b1 = *(const short8*)(Bl + (c0 + 16 + m) * LDP + ko);
#pragma unroll
      for (int rt = 0; rt < 4; ++rt) {
        short8 av = *(const short8*)(Al + (rt * 16 + m) * LDP + ko);
        acc[rt][0] = __builtin_amdgcn_mfma_f32_16x16x32_bf16(av, b0, acc[rt][0], 0, 0, 0);
        acc[rt][1] = __builtin_amdgcn_mfma_f32_16x16x32_bf16(av, b1, acc[rt][1], 0, 0, 0);
      }
    }
  }

#pragma unroll
  for (int ct = 0; ct < 2; ++ct) {
    int col = c0 + ct * 16 + m;
    float bs = bsum[col];
#pragma unroll
    for (int rt = 0; rt < 4; ++rt) {
#pragma unroll
      for (int i = 0; i < 4; ++i) {
        int row = row0 + rt * 16 + q * 4 + i;
        if (row < n) out[(size_t)row * C + col] = acc[rt][ct][i] + bs;
      }
    }
  }
}

extern "C" void kernel_launch(void* const* d_in, const int* in_sizes, int n_in,
                              void* d_out, int out_size, void* d_ws, size_t ws_size,
                              hipStream_t stream) {
  const float* nodes = (const float*)d_in[0];
  const float* edges = (const float*)d_in[1];
  const int* senders = (const int*)d_in[2];
  const int* receivers = (const int*)d_in[3];
  const float* W = (const float*)d_in[4];
  const float* b_dense = (const float*)d_in[5];
  const float* bias = (const float*)d_in[6];
  float* out = (float*)d_out;
  int n = in_sizes[0] / C;
  int ne = in_sizes[1];
  int NB = (ne + EPB - 1) / EPB;          // phase-1 blocks
  int NBUCK = (n + 255) >> 8;             // coarse buckets (sender>>8)
  int M = 256 * NB;                       // scan table length
  int nb2 = (M + 1023) / 1024;

  char* ws = (char*)d_ws;
  size_t off = 0;
  auto alloc = [&](size_t b) { size_t r = off; off += (b + 255) & ~(size_t)255; return r; };
  float* degf = (float*)(ws + alloc((size_t)n * 4));
  int* offsets = (int*)(ws + alloc((size_t)(n + 1) * 4));
  int* hist = (int*)(ws + alloc((size_t)M * 4));
  int* bsums = (int*)(ws + alloc((size_t)nb2 * 4));
  int2* bkt = (int2*)(ws + alloc((size_t)ne * 8));
  int2* csr_wr = (int2*)(ws + alloc((size_t)ne * 8));
  unsigned* umax = (unsigned*)(ws + alloc(4));
  float* scalep = (float*)(ws + alloc(4));
  float* bsum = (float*)(ws + alloc(C * 4));
  short* Xb = (short*)(ws + alloc((size_t)n * KD * 2));
  short* Wt = (short*)(ws + alloc((size_t)KD * C * 2));
  (void)ws_size; (void)n_in; (void)out_size;

  hipMemsetAsync(umax, 0, 4, stream);

  prep_kernel<<<(KD * C + 255) / 256, 256, 0, stream>>>(W, b_dense, bias, Wt, bsum);
  cvt_nodes_kernel<<<(n * 32 + 255) / 256, 256, 0, stream>>>(nodes, Xb, n);

  // CSR build — no global atomics (LDS atomics + scans only)
  p1_count_kernel<<<NB, 256, 0, stream>>>(senders, edges, ne, hist, NB, umax);
  scan1_kernel<<<nb2, 1024, 0, stream>>>(hist, hist, bsums, M);
  scan2_kernel<<<1, 1024, 0, stream>>>(bsums, nb2);
  scan3_kernel<<<(M + 255) / 256, 256, 0, stream>>>(hist, bsums, M);
  p1_scatter_kernel<<<NB, 256, 0, stream>>>(senders, receivers, edges, ne, hist, NB, bkt);
  p2_finalize_kernel<<<NBUCK, 256, 0, stream>>>(bkt, hist, NB, NBUCK, ne, n, csr_wr, offsets,
                                                degf, umax);
  scale_kernel<<<1, 1, 0, stream>>>(umax, scalep);

  int mvblocks = (n * 64 + 255) / 256;

  // Chebyshev recurrence, all state bf16 in Xb slots:
  // Tx1 = L̂ Tx0
  matvec_kernel<<<mvblocks, 256, 0, stream>>>(Xb + 0 * C, nullptr, Xb + 1 * C,
                                              degf, offsets, csr_wr, scalep, 1.0f, n);
  // Tx_k = 2 L̂ Tx_{k-1} - Tx_{k-2}
  matvec_kernel<<<mvblocks, 256, 0, stream>>>(Xb + 1 * C, Xb + 0 * C, Xb + 2 * C,
                                              degf, offsets, csr_wr, scalep, 2.0f, n);
  matvec_kernel<<<mvblocks, 256, 0, stream>>>(Xb + 2 * C, Xb + 1 * C, Xb + 3 * C,
                                              degf, offsets, csr_wr, scalep, 2.0f, n);
  matvec_kernel<<<mvblocks, 256, 0, stream>>>(Xb + 3 * C, Xb + 2 * C, Xb + 4 * C,
                                              degf, offsets, csr_wr, scalep, 2.0f, n);
  matvec_kernel<<<mvblocks, 256, 0, stream>>>(Xb + 4 * C, Xb + 3 * C, Xb + 5 * C,
                                              degf, offsets, csr_wr, scalep, 2.0f, n);

  // out = Xb @ vstack(W) + (sum_k b_k + bias), LDS-staged MFMA GEMM
  mfma_gemm_kernel<<<(n + 63) / 64, 256, 0, stream>>>(Xb, Wt, bsum, out, n);
}